// Round 12
// baseline (869.277 us; speedup 1.0000x reference)
//
#include <hip/hip_runtime.h>
#include <hip/hip_bf16.h>

#define XSTR 28   // legacy BN VALU kernel stride

typedef short short8 __attribute__((ext_vector_type(8)));
typedef float f32x4  __attribute__((ext_vector_type(4)));
typedef float f32x16 __attribute__((ext_vector_type(16)));

__device__ __forceinline__ float gelu_f(float x){
    return 0.5f*x*(1.0f + erff(x*0.70710678118654752f));
}
// fast gelu, tanh form: x*sigmoid(1.5958(x+0.044715x^3)), |err| <= ~3e-4
__device__ __forceinline__ float gelu_q(float x){
    const float z = 1.5957691216057308f*x*(1.0f + 0.044715f*x*x);
    return x / (1.0f + __expf(-z));
}
__device__ __forceinline__ unsigned short f2bf(float f){
    unsigned int u = __float_as_uint(f);
    u += 0x7fffu + ((u>>16)&1u);
    return (unsigned short)(u>>16);
}
__device__ __forceinline__ unsigned int pack2(float a, float b){
    return (unsigned int)f2bf(a) | ((unsigned int)f2bf(b)<<16);
}
__device__ __forceinline__ float bf_lo(unsigned int u){ return __uint_as_float(u<<16); }
__device__ __forceinline__ float bf_hi(unsigned int u){ return __uint_as_float(u & 0xffff0000u); }
__device__ __forceinline__ float bfu(unsigned short v){ return __uint_as_float(((unsigned int)v)<<16); }

__device__ __forceinline__ void fma_row25(const float* __restrict__ row, float w, float* __restrict__ acc){
    const float4* r4 = (const float4*)row;
    float4 a0=r4[0], a1=r4[1], a2=r4[2], a3=r4[3], a4=r4[4], a5=r4[5];
    float a6 = row[24];
    acc[0]+=a0.x*w;  acc[1]+=a0.y*w;  acc[2]+=a0.z*w;  acc[3]+=a0.w*w;
    acc[4]+=a1.x*w;  acc[5]+=a1.y*w;  acc[6]+=a1.z*w;  acc[7]+=a1.w*w;
    acc[8]+=a2.x*w;  acc[9]+=a2.y*w;  acc[10]+=a2.z*w; acc[11]+=a2.w*w;
    acc[12]+=a3.x*w; acc[13]+=a3.y*w; acc[14]+=a3.z*w; acc[15]+=a3.w*w;
    acc[16]+=a4.x*w; acc[17]+=a4.y*w; acc[18]+=a4.z*w; acc[19]+=a4.w*w;
    acc[20]+=a5.x*w; acc[21]+=a5.y*w; acc[22]+=a5.z*w; acc[23]+=a5.w*w;
    acc[24]+=a6*w;
}

// ================= BN body (proven r7-r11), LDS passed in =================
__device__ __forceinline__ void bn_body(
    unsigned char* __restrict__ U, int n0, int t,
    const float* __restrict__ bottleneck, const float* __restrict__ pos,
    const float* __restrict__ dw_w, const float* __restrict__ dw_b,
    const float* __restrict__ ln_g, const float* __restrict__ ln_b,
    const float* __restrict__ pw1_b, const float* __restrict__ pw2_b,
    const float* __restrict__ cn_gamma, const float* __restrict__ bn1x1_b,
    const short8* __restrict__ P1v, const short8* __restrict__ P2v,
    const short8* __restrict__ Pbv,
    float* __restrict__ vec_out)
{
    unsigned char* Xb = U;                       // 32768
    unsigned char* Hc = U + 32768;               // 16384
    float* redA = (float*)(U + 49152);           // 1600
    float* redB = (float*)(U + 50752);           // 1600
    float* muS  = (float*)(U + 52352);           // 224
    float* rsS  = (float*)(U + 52576);           // 224  -> 52800 total

    const int lane = t & 63, w = t >> 6;
    const int mcol = lane & 15, h4 = lane >> 4;
    const int sP = t >> 8, cP = t & 255;

    unsigned int wvp[13];
    float xdw[25];
    {
        const int n = n0 + sP;
        const float px = pos[2*n]*0.125f, py = pos[2*n+1]*0.125f;
        const float fpx = floorf(px), fpy = floorf(py);
        const int ix0 = (int)fpx - 2, iy0 = (int)fpy - 2;
        const float fx = px - fpx, fy = py - fpy;
        const float w00=(1.f-fy)*(1.f-fx), w01=(1.f-fy)*fx, w10=fy*(1.f-fx), w11=fy*fx;
        float wv[25];
        {
            const float* fm = bottleneck + cP*16384;
            float P[6][6];
            #pragma unroll
            for (int r=0;r<6;r++){
                const int y = iy0+r;
                const bool yok = (y>=0)&&(y<128);
                const int yc = y<0?0:(y>127?127:y);
                #pragma unroll
                for (int s=0;s<6;s++){
                    const int x = ix0+s;
                    const bool ok = yok && (x>=0) && (x<128);
                    const int xc = x<0?0:(x>127?127:x);
                    P[r][s] = ok ? fm[yc*128+xc] : 0.f;
                }
            }
            #pragma unroll
            for (int a=0;a<5;a++)
            #pragma unroll
            for (int b=0;b<5;b++)
                wv[a*5+b] = w00*P[a][b]+w01*P[a][b+1]+w10*P[a+1][b]+w11*P[a+1][b+1];
        }
        #pragma unroll
        for (int i=0;i<12;i++) wvp[i] = pack2(wv[2*i], wv[2*i+1]);
        wvp[12] = pack2(wv[24], 0.f);
        {
            float wcr[49];
            const float* wc = dw_w + cP*49;
            #pragma unroll
            for (int k=0;k<49;k++) wcr[k]=wc[k];
            const float bb = dw_b[cP];
            #pragma unroll
            for (int i=0;i<5;i++){
                #pragma unroll
                for (int j=0;j<5;j++){
                    float a = bb;
                    #pragma unroll
                    for (int u=0;u<7;u++){
                        const int y = i+u-3;
                        if (y<0||y>4) continue;
                        #pragma unroll
                        for (int v=0;v<7;v++){
                            const int x = j+v-3;
                            if (x<0||x>4) continue;
                            a += wv[y*5+x]*wcr[u*7+v];
                        }
                    }
                    xdw[i*5+j] = a;
                }
            }
        }
        #pragma unroll
        for (int p=0;p<25;p++){
            const int row = sP*32 + p;
            *(unsigned short*)(Xb + row*512 + ((2*cP) ^ ((row&7)<<4))) = f2bf(xdw[p]);
        }
    }
    __syncthreads();
    if (t < 400){
        const int sp = t>>3, part = t&7;
        const int row = (sp/25)*32 + (sp - (sp/25)*25);
        float a=0.f, b=0.f;
        for (int c=part; c<256; c+=8){
            const float v = bfu(*(const unsigned short*)(Xb + row*512 + ((2*c) ^ ((row&7)<<4))));
            a += v; b += v*v;
        }
        redA[t]=a; redB[t]=b;
    }
    __syncthreads();
    if (t < 50){
        float a=0.f, b=0.f;
        #pragma unroll
        for (int s=0;s<8;s++){ a+=redA[t*8+s]; b+=redB[t*8+s]; }
        const float m = a*(1.f/256.f);
        const float var = b*(1.f/256.f) - m*m;
        muS[t]=m; rsS[t]=rsqrtf(var+1e-6f);
    }
    __syncthreads();
    {
        const float g = ln_g[cP], bb = ln_b[cP];
        #pragma unroll
        for (int p=0;p<25;p++){
            const int row = sP*32 + p;
            const float v = (xdw[p]-muS[sP*25+p])*rsS[sP*25+p]*g + bb;
            *(unsigned short*)(Xb + row*512 + ((2*cP) ^ ((row&7)<<4))) = f2bf(v);
        }
    }
    __syncthreads();

    f32x4 acc2[2][4];
    #pragma unroll
    for (int ml=0;ml<2;ml++)
        #pragma unroll
        for (int nt=0;nt<4;nt++) acc2[ml][nt]=0.f;

    for (int ch=0; ch<8; ++ch){
        const int mt = ch*8 + w;
        f32x4 a1[4];
        #pragma unroll
        for (int nt=0;nt<4;nt++) a1[nt]=0.f;
        #pragma unroll
        for (int kk=0; kk<8; ++kk){
            const short8 av = P1v[((mt<<3)+kk)*64 + lane];
            #pragma unroll
            for (int nt=0; nt<4; ++nt){
                const int row = nt*16 + mcol;
                const int ad = row*512 + ((kk*64 + h4*16) ^ ((row&7)<<4));
                const short8 bv = *(const short8*)(Xb + ad);
                a1[nt] = __builtin_amdgcn_mfma_f32_16x16x32_bf16(av, bv, a1[nt], 0,0,0);
            }
        }
        {
            const float4 b1v = *(const float4*)(pw1_b + mt*16 + h4*4);
            #pragma unroll
            for (int nt=0; nt<4; ++nt){
                const int row = nt*16 + mcol;
                const float g0 = gelu_q(a1[nt].x + b1v.x);
                const float g1 = gelu_q(a1[nt].y + b1v.y);
                const float g2 = gelu_q(a1[nt].z + b1v.z);
                const float g3 = gelu_q(a1[nt].w + b1v.w);
                const int ad = row*256 + ((w*32 + h4*8) ^ ((row&7)<<4));
                *(uint2*)(Hc + ad) = make_uint2(pack2(g0,g1), pack2(g2,g3));
            }
        }
        __syncthreads();
        #pragma unroll
        for (int ml=0; ml<2; ++ml){
            const int mtc = w*2 + ml;
            #pragma unroll
            for (int kk2=0; kk2<4; ++kk2){
                const short8 av = P2v[(mtc*32 + (ch*4 + kk2))*64 + lane];
                #pragma unroll
                for (int nt=0; nt<4; ++nt){
                    const int row = nt*16 + mcol;
                    const int ad = row*256 + ((kk2*64 + h4*16) ^ ((row&7)<<4));
                    const short8 bv = *(const short8*)(Hc + ad);
                    acc2[ml][nt] = __builtin_amdgcn_mfma_f32_16x16x32_bf16(av, bv, acc2[ml][nt], 0,0,0);
                }
            }
        }
        __syncthreads();
    }

    #pragma unroll
    for (int ml=0; ml<2; ++ml){
        const int c0 = (w*2+ml)*16 + h4*4;
        const float4 gm = *(const float4*)(cn_gamma + c0);
        const float4 b2 = *(const float4*)(pw2_b + c0);
        #pragma unroll
        for (int nt=0; nt<4; ++nt){
            const int row = nt*16 + mcol;
            const int ad = row*512 + ((2*c0) ^ ((row&7)<<4));
            const float f0 = gm.x*(acc2[ml][nt].x + b2.x);
            const float f1 = gm.y*(acc2[ml][nt].y + b2.y);
            const float f2 = gm.z*(acc2[ml][nt].z + b2.z);
            const float f3 = gm.w*(acc2[ml][nt].w + b2.w);
            *(uint2*)(Xb + ad) = make_uint2(pack2(f0,f1), pack2(f2,f3));
        }
    }
    __syncthreads();
    #pragma unroll
    for (int p=0;p<25;p++){
        const int row = sP*32 + p;
        unsigned short* ptr = (unsigned short*)(Xb + row*512 + ((2*cP) ^ ((row&7)<<4)));
        const float r = (p&1) ? bf_hi(wvp[p>>1]) : bf_lo(wvp[p>>1]);
        *ptr = f2bf(bfu(*ptr) + r);
    }
    __syncthreads();

    {
        f32x4 a3[4];
        #pragma unroll
        for (int nt=0;nt<4;nt++) a3[nt]=0.f;
        #pragma unroll
        for (int kk=0; kk<8; ++kk){
            const short8 av = Pbv[((w<<3)+kk)*64 + lane];
            #pragma unroll
            for (int nt=0; nt<4; ++nt){
                const int row = nt*16 + mcol;
                const int ad = row*512 + ((kk*64 + h4*16) ^ ((row&7)<<4));
                const short8 bv = *(const short8*)(Xb + ad);
                a3[nt] = __builtin_amdgcn_mfma_f32_16x16x32_bf16(av, bv, a3[nt], 0,0,0);
            }
        }
        const float4 bb = *(const float4*)(bn1x1_b + w*16 + h4*4);
        float e5[5];
        #pragma unroll
        for (int a=0;a<5;a++){
            const float ta = -1.f + 0.5f*a;
            e5[a] = expf(-3.125f*ta*ta);
        }
        const float Sv = e5[0]+e5[1]+e5[2]+e5[3]+e5[4];
        const float invS = 1.0f/(Sv*Sv);
        float sA[2][4];
        #pragma unroll
        for (int s=0;s<2;s++)
            #pragma unroll
            for (int j=0;j<4;j++) sA[s][j]=0.f;
        #pragma unroll
        for (int nt=0; nt<4; ++nt){
            const int row = nt*16 + mcol;
            const int s = row>>5, p = row&31;
            if (p < 25){
                const int pa = p/5, pb = p - pa*5;
                const float g = e5[pa]*e5[pb];
                sA[s][0] += g*gelu_q(a3[nt].x + bb.x);
                sA[s][1] += g*gelu_q(a3[nt].y + bb.y);
                sA[s][2] += g*gelu_q(a3[nt].z + bb.z);
                sA[s][3] += g*gelu_q(a3[nt].w + bb.w);
            }
        }
        #pragma unroll
        for (int off=1; off<16; off<<=1){
            #pragma unroll
            for (int s=0;s<2;s++)
                #pragma unroll
                for (int j=0;j<4;j++) sA[s][j] += __shfl_xor(sA[s][j], off);
        }
        if (mcol == 0){
            const int o = w*16 + h4*4;
            #pragma unroll
            for (int s=0;s<2;s++){
                float* vo = vec_out + (n0+s)*192 + o;
                vo[0]=sA[s][0]*invS; vo[1]=sA[s][1]*invS;
                vo[2]=sA[s][2]*invS; vo[3]=sA[s][3]*invS;
            }
        }
    }
}

// ================= Stem body (proven r9-r11), LDS passed in =================
#define STEM_CONV32(SRC, AP)                                                        \
    _Pragma("unroll")                                                               \
    for (int k=0;k<9;k++){                                                          \
        int tj[3];                                                                  \
        _Pragma("unroll")                                                           \
        for (int j=0;j<3;j++)                                                       \
            tj[j] = (int)sTab[m*90 + (j<cnt ? st+j : st)*9 + k];                    \
        _Pragma("unroll")                                                           \
        for (int kt=0;kt<4;kt++){                                                   \
            const short8 av = (AP)[(k*8 + kt*2 + wo)*64 + lane];                    \
            const int cb = kt*32 + hi16;                                            \
            _Pragma("unroll")                                                       \
            for (int j=0;j<3;j++){                                                  \
                if (j < cnt){                                                       \
                    const short8 bv = *(const short8*)((SRC) + (tj[j] ^ cb));       \
                    acc[j] = __builtin_amdgcn_mfma_f32_32x32x16_bf16(av, bv, acc[j], 0,0,0); \
                }                                                                   \
            }                                                                       \
        }                                                                           \
    }

__device__ __forceinline__ void stem_body(
    unsigned char* __restrict__ U, int n, int t,
    const float* __restrict__ vis, const float* __restrict__ pos,
    const short8* __restrict__ Ap1,
    const float* __restrict__ st1_b, const float* __restrict__ st2_b,
    float* __restrict__ vec_out)
{
    unsigned char* sXt = U;                                  // 37120
    unsigned short* sTab = (unsigned short*)(U + 37120);     // 5760
    float (*redS)[4] = (float(*)[4])(U + 42880);             // 1024 -> 43904

    const int lane = t & 63;
    const int m = lane & 31;
    const int hi = lane >> 5;
    const int hi16 = hi*16;
    const int w = t >> 6;
    const int wo = w & 1;
    const int nh = w >> 1;
    const int st  = nh*3 - (nh==3 ? 1 : 0);
    const int cnt = (nh < 2) ? 3 : 2;

    const float fpx0 = pos[2*n], fpy0 = pos[2*n+1];
    const float fpx = floorf(fpx0), fpy = floorf(fpy0);
    const int ix0 = (int)fpx - 8, iy0 = (int)fpy - 8;
    const float fx = fpx0-fpx, fy = fpy0-fpy;
    const float w00=(1.f-fy)*(1.f-fx), w01=(1.f-fy)*fx, w10=fy*(1.f-fx), w11=fy*fx;

    if (t < 32) *(unsigned int*)(sXt + 289*128 + t*4) = 0u;

    for (int idx = t; idx < 32*90; idx += 512){
        const int mm = idx/90, rem = idx - mm*90;
        const int nt = rem/9, k = rem - nt*9;
        const int p = nt*32 + mm;
        int pp = 289;
        if (p < 289){
            const int py = (p*241)>>12, px = p - py*17;
            const int y = py + k/3 - 1, x = px + (k - (k/3)*3) - 1;
            if (((unsigned)y < 17u) && ((unsigned)x < 17u)) pp = y*17 + x;
        }
        sTab[idx] = (unsigned short)(pp*128 + ((pp&7)<<4));
    }

    for (int task = t; task < 64*17; task += 512){
        const int c  = task & 63;
        const int py = task >> 6;
        const float* r0 = vis + c*1048576 + (iy0+py)*1024 + ix0;
        float a[18], b[18];
        #pragma unroll
        for (int kk=0; kk<18; kk++){ a[kk]=r0[kk]; b[kk]=r0[1024+kk]; }
        #pragma unroll
        for (int px=0; px<17; px++){
            const float v = w00*a[px] + w01*a[px+1] + w10*b[px] + w11*b[px+1];
            const int p = py*17 + px;
            *(unsigned short*)(sXt + p*128 + ((2*c) ^ ((p&7)<<4))) = f2bf(v);
        }
    }
    __syncthreads();

    f32x16 acc[3];
    #pragma unroll
    for (int j=0;j<3;j++) acc[j] = 0.f;
    STEM_CONV32(sXt, Ap1)

    uint2 pk[3][4];
    {
        float4 b4[4];
        #pragma unroll
        for (int rg=0;rg<4;rg++) b4[rg] = *(const float4*)(st1_b + wo*32 + 8*rg + 4*hi);
        #pragma unroll
        for (int j=0;j<3;j++){
            if (j < cnt){
                #pragma unroll
                for (int rg=0;rg<4;rg++){
                    const float v0 = gelu_q(acc[j][4*rg+0] + b4[rg].x);
                    const float v1 = gelu_q(acc[j][4*rg+1] + b4[rg].y);
                    const float v2 = gelu_q(acc[j][4*rg+2] + b4[rg].z);
                    const float v3 = gelu_q(acc[j][4*rg+3] + b4[rg].w);
                    pk[j][rg] = make_uint2(pack2(v0,v1), pack2(v2,v3));
                }
            }
        }
    }
    __syncthreads();

    #pragma unroll
    for (int j=0;j<3;j++){
        if (j < cnt){
            const int p = (st+j)*32 + m;
            if (p < 289){
                const int swz = (p&7)<<4;
                #pragma unroll
                for (int rg=0;rg<4;rg++){
                    const int ch0 = wo*32 + 8*rg + 4*hi;
                    *(uint2*)(sXt + p*128 + ((2*ch0) ^ swz)) = pk[j][rg];
                }
            }
        }
    }
    __syncthreads();

    const short8* Ap2 = Ap1 + 4608;
    #pragma unroll
    for (int j=0;j<3;j++) acc[j] = 0.f;
    STEM_CONV32(sXt, Ap2)

    {
        float4 b4[4];
        #pragma unroll
        for (int rg=0;rg<4;rg++) b4[rg] = *(const float4*)(st2_b + wo*32 + 8*rg + 4*hi);
        float s[16];
        #pragma unroll
        for (int r=0;r<16;r++) s[r]=0.f;
        #pragma unroll
        for (int j=0;j<3;j++){
            if (j < cnt){
                const int p = (st+j)*32 + m;
                if (p < 289){
                    const int py = (p*241)>>12;
                    const int px = p - py*17;
                    const float ty = -1.f + 0.125f*py;
                    const float tx = -1.f + 0.125f*px;
                    const float g = expf(-3.125f*(ty*ty + tx*tx));
                    #pragma unroll
                    for (int rg=0;rg<4;rg++){
                        s[4*rg+0] += g*gelu_q(acc[j][4*rg+0] + b4[rg].x);
                        s[4*rg+1] += g*gelu_q(acc[j][4*rg+1] + b4[rg].y);
                        s[4*rg+2] += g*gelu_q(acc[j][4*rg+2] + b4[rg].z);
                        s[4*rg+3] += g*gelu_q(acc[j][4*rg+3] + b4[rg].w);
                    }
                }
            }
        }
        #pragma unroll
        for (int off=1; off<32; off<<=1){
            #pragma unroll
            for (int r=0;r<16;r++) s[r] += __shfl_xor(s[r], off);
        }
        if (m == 0){
            #pragma unroll
            for (int rg=0;rg<4;rg++)
                #pragma unroll
                for (int e=0;e<4;e++)
                    redS[wo*32 + 8*rg + 4*hi + e][nh] = s[4*rg+e];
        }
    }
    __syncthreads();
    if (t < 64){
        float Sv = 0.f;
        #pragma unroll
        for (int j=0;j<17;j++){
            const float tj = -1.f + 0.125f*j;
            Sv += expf(-3.125f*tj*tj);
        }
        vec_out[n*192+128+t] = (redS[t][0] + redS[t][1] + redS[t][2] + redS[t][3]) / (Sv*Sv);
    }
}

// ================= Fused fat kernel: interleaved bn-pair / stem blocks =================
// b%3==0 -> bn pair b/3 ; b%3 in {1,2} -> stem sample (b/3)*2 + b%3 - 1.
// Interleaving keeps every CU populated with a MIX of bn (VALU-heavy) and stem
// (LDS/MFMA-heavy) waves so their stall bubbles overlap.
__global__ __launch_bounds__(512,4) void fused_branches(
    const float* __restrict__ bottleneck, const float* __restrict__ vis,
    const float* __restrict__ pos,
    const float* __restrict__ dw_w, const float* __restrict__ dw_b,
    const float* __restrict__ ln_g, const float* __restrict__ ln_b,
    const float* __restrict__ pw1_b, const float* __restrict__ pw2_b,
    const float* __restrict__ cn_gamma, const float* __restrict__ bn1x1_b,
    const short8* __restrict__ P1v, const short8* __restrict__ P2v,
    const short8* __restrict__ Pbv,
    const short8* __restrict__ Ap1,
    const float* __restrict__ st1_b, const float* __restrict__ st2_b,
    float* __restrict__ vec_out)
{
    __shared__ __align__(16) unsigned char U[52800];
    const int b = blockIdx.x, t = threadIdx.x;
    const int q = b/3, r = b - q*3;
    if (r == 0){
        bn_body(U, q*2, t, bottleneck, pos, dw_w, dw_b, ln_g, ln_b,
                pw1_b, pw2_b, cn_gamma, bn1x1_b, P1v, P2v, Pbv, vec_out);
    } else {
        stem_body(U, q*2 + r - 1, t, vis, pos, Ap1, st1_b, st2_b, vec_out);
    }
}

// ---- bn weight prepack (proven) ----
__global__ __launch_bounds__(256) void prepack_bn_kernel(
    const float* __restrict__ W1, const float* __restrict__ W2, const float* __restrict__ Wb,
    unsigned short* __restrict__ P1, unsigned short* __restrict__ P2, unsigned short* __restrict__ Pb)
{
    const int tid = blockIdx.x*256 + threadIdx.x;
    const float* src; unsigned short* dst; int row, col, stride, idx;
    if (tid < 32768){
        idx = tid;
        const int frag = idx>>6, l = idx&63;
        row = (frag>>3)*16 + (l&15); col = (frag&7)*32 + (l>>4)*8; stride = 256;
        src = W1; dst = P1;
    } else if (tid < 65536){
        idx = tid - 32768;
        const int frag = idx>>6, l = idx&63;
        row = (frag>>5)*16 + (l&15); col = (frag&31)*32 + (l>>4)*8; stride = 1024;
        src = W2; dst = P2;
    } else if (tid < 69632){
        idx = tid - 65536;
        const int frag = idx>>6, l = idx&63;
        row = (frag>>3)*16 + (l&15); col = (frag&7)*32 + (l>>4)*8; stride = 256;
        src = Wb; dst = Pb;
    } else return;
    const float* s = src + row*stride + col;
    unsigned int v[4];
    #pragma unroll
    for (int j=0;j<4;j++) v[j] = pack2(s[2*j], s[2*j+1]);
    *(uint4*)(dst + (size_t)idx*8) = make_uint4(v[0],v[1],v[2],v[3]);
}

// ================= BN branch, VALU fallback (proven) =================
__global__ __launch_bounds__(256,2) void bn_branch_valu(
    const float* __restrict__ bottleneck, const float* __restrict__ pos,
    const float* __restrict__ dw_w, const float* __restrict__ dw_b,
    const float* __restrict__ ln_g, const float* __restrict__ ln_b,
    const float* __restrict__ pw1_w, const float* __restrict__ pw1_b,
    const float* __restrict__ pw2_w, const float* __restrict__ pw2_b,
    const float* __restrict__ cn_gamma,
    const float* __restrict__ bn1x1_w, const float* __restrict__ bn1x1_b,
    float* __restrict__ vec_out)
{
    __shared__ float xln[256*XSTR];
    __shared__ float hbuf[256*XSTR];
    __shared__ float redA[200], redB[200];
    __shared__ float mu[25], rs[25];

    const int n = blockIdx.x;
    const int t = threadIdx.x;
    const int c = t;

    const float px = pos[2*n]*0.125f, py = pos[2*n+1]*0.125f;
    const float fpx = floorf(px), fpy = floorf(py);
    const int ix0 = (int)fpx - 2, iy0 = (int)fpy - 2;
    const float fx = px - fpx, fy = py - fpy;
    const float w00=(1.f-fy)*(1.f-fx), w01=(1.f-fy)*fx, w10=fy*(1.f-fx), w11=fy*fx;

    float wv[25];
    {
        const float* fm = bottleneck + c*16384;
        float P[6][6];
        #pragma unroll
        for (int r=0;r<6;r++){
            const int y = iy0+r;
            const bool yok = (y>=0)&&(y<128);
            const int yc = y<0?0:(y>127?127:y);
            #pragma unroll
            for (int s=0;s<6;s++){
                const int x = ix0+s;
                const bool ok = yok && (x>=0) && (x<128);
                const int xc = x<0?0:(x>127?127:x);
                P[r][s] = ok ? fm[yc*128+xc] : 0.f;
            }
        }
        #pragma unroll
        for (int a=0;a<5;a++)
        #pragma unroll
        for (int b=0;b<5;b++)
            wv[a*5+b] = w00*P[a][b]+w01*P[a][b+1]+w10*P[a+1][b]+w11*P[a+1][b+1];
    }
    {
        float wcr[49];
        const float* wc = dw_w + c*49;
        #pragma unroll
        for (int k=0;k<49;k++) wcr[k]=wc[k];
        const float bb = dw_b[c];
        #pragma unroll
        for (int i=0;i<5;i++){
            #pragma unroll
            for (int j=0;j<5;j++){
                float a = bb;
                #pragma unroll
                for (int u=0;u<7;u++){
                    const int y = i+u-3;
                    if (y<0||y>4) continue;
                    #pragma unroll
                    for (int v=0;v<7;v++){
                        const int x = j+v-3;
                        if (x<0||x>4) continue;
                        a += wv[y*5+x]*wcr[u*7+v];
                    }
                }
                xln[c*XSTR + i*5+j] = a;
            }
        }
    }
    __syncthreads();
    if (t < 200){
        const int p = t>>3, s = t&7;
        float a=0.f, b=0.f;
        for (int cc=s; cc<256; cc+=8){
            const float v = xln[cc*XSTR+p];
            a += v; b += v*v;
        }
        redA[t]=a; redB[t]=b;
    }
    __syncthreads();
    if (t < 25){
        float a=0.f, b=0.f;
        #pragma unroll
        for (int s=0;s<8;s++){ a+=redA[t*8+s]; b+=redB[t*8+s]; }
        const float m = a*(1.f/256.f);
        const float var = b*(1.f/256.f) - m*m;
        mu[t]=m; rs[t]=rsqrtf(var+1e-6f);
    }
    __syncthreads();
    {
        const float g = ln_g[c], bb = ln_b[c];
        #pragma unroll
        for (int p=0;p<25;p++)
            xln[c*XSTR+p] = (xln[c*XSTR+p]-mu[p])*rs[p]*g + bb;
    }
    __syncthreads();
    float acc2[25];
    #pragma unroll
    for (int p=0;p<25;p++) acc2[p]=0.f;
    for (int r=0;r<4;r++){
        const int o = r*256 + t;
        float h[25];
        {
            const float b1 = pw1_b[o];
            #pragma unroll
            for (int p=0;p<25;p++) h[p]=b1;
            const float* wr = pw1_w + o*256;
            for (int cc=0;cc<256;cc++)
                fma_row25(xln + cc*XSTR, wr[cc], h);
            #pragma unroll
            for (int p=0;p<25;p++) h[p]=gelu_f(h[p]);
        }
        __syncthreads();
        #pragma unroll
        for (int p=0;p<25;p++) hbuf[t*XSTR+p]=h[p];
        __syncthreads();
        {
            const float* w2 = pw2_w + t*1024 + r*256;
            for (int k=0;k<256;k++)
                fma_row25(hbuf + k*XSTR, w2[k], acc2);
        }
    }
    {
        const float gam = cn_gamma[c], b2 = pw2_b[c];
        #pragma unroll
        for (int p=0;p<25;p++)
            xln[c*XSTR+p] = wv[p] + gam*(acc2[p]+b2);
    }
    __syncthreads();
    if (t < 128){
        float acc[25];
        #pragma unroll
        for (int p=0;p<25;p++) acc[p]=0.f;
        const float* wr = bn1x1_w + t*256;
        for (int cc=0;cc<256;cc++)
            fma_row25(xln + cc*XSTR, wr[cc], acc);
        const float b = bn1x1_b[t];
        float e5[5];
        #pragma unroll
        for (int a=0;a<5;a++){
            const float ta = -1.f + 0.5f*a;
            e5[a] = expf(-3.125f*ta*ta);
        }
        const float Sv = e5[0]+e5[1]+e5[2]+e5[3]+e5[4];
        float res = 0.f;
        #pragma unroll
        for (int a=0;a<5;a++){
            float rowa = 0.f;
            #pragma unroll
            for (int bb=0;bb<5;bb++)
                rowa += e5[bb]*gelu_f(acc[a*5+bb]+b);
            res += e5[a]*rowa;
        }
        vec_out[n*192+t] = res/(Sv*Sv);
    }
}

// ---------------- Stem weight prepack: 32x32x16 A-fragment layout (proven r9) ----------------
__global__ __launch_bounds__(256) void prepack_kernel(
    const float* __restrict__ W1, const float* __restrict__ W2,
    unsigned short* __restrict__ Ap)
{
    const int tid = blockIdx.x*256 + threadIdx.x;
    if (tid >= 9216) return;
    const int conv = tid / 4608;
    const int r = tid - conv*4608;
    const int frag = r >> 6, l = r & 63;
    const int k  = frag >> 3;
    const int kt = (frag >> 1) & 3;
    const int wo = frag & 1;
    const float* W = conv ? W2 : W1;
    const int o  = wo*32 + (l & 31);
    const int c0 = kt*16 + (l >> 5)*8;
    unsigned int v[4];
    #pragma unroll
    for (int jj=0; jj<4; jj++){
        const float f0 = W[o*576 + (c0+2*jj  )*9 + k];
        const float f1 = W[o*576 + (c0+2*jj+1)*9 + k];
        v[jj] = pack2(f0, f1);
    }
    *(uint4*)(Ap + (size_t)tid*8) = make_uint4(v[0], v[1], v[2], v[3]);
}

// ---------------- Stem standalone (fallback path only) ----------------
__global__ __launch_bounds__(512,4) void stem_branch_kernel(
    const float* __restrict__ vis,
    const float* __restrict__ pos,
    const short8* __restrict__ Ap1,
    const float* __restrict__ st1_b,
    const float* __restrict__ st2_b,
    float* __restrict__ vec_out)
{
    __shared__ __align__(16) unsigned char U[43904];
    stem_body(U, blockIdx.x, threadIdx.x, vis, pos, Ap1, st1_b, st2_b, vec_out);
}

// ---------------- Head: 16 samples/block (proven) ----------------
__global__ __launch_bounds__(128) void head16_kernel(
    const float* __restrict__ vec, const float* __restrict__ p2s,
    const float* __restrict__ h1_w, const float* __restrict__ h1_b,
    const float* __restrict__ h2_w, const float* __restrict__ h2_b,
    const float* __restrict__ h3_w, const float* __restrict__ h3_b,
    float* __restrict__ out, int N)
{
    __shared__ float v[16][192];
    __shared__ float x1s[16][132];
    __shared__ float x2s[16][132];
    __shared__ float o3s[16][4];
    const int n0 = blockIdx.x*16, t = threadIdx.x;

    for (int idx=t; idx<16*192; idx+=128){
        const int s = idx/192, k = idx - s*192;
        v[s][k] = vec[n0*192 + idx];
    }
    __syncthreads();
    {
        const int o = t;
        float acc[16];
        const float b = h1_b[o];
        #pragma unroll
        for (int s=0;s<16;s++) acc[s]=b;
        const float4* wr = (const float4*)(h1_w + o*192);
        for (int k4=0;k4<48;k4++){
            const float4 wv4 = wr[k4];
            #pragma unroll
            for (int s=0;s<16;s++){
                const float4 vv = *(const float4*)&v[s][k4*4];
                acc[s] += wv4.x*vv.x + wv4.y*vv.y + wv4.z*vv.z + wv4.w*vv.w;
            }
        }
        #pragma unroll
        for (int s=0;s<16;s++) x1s[s][o] = gelu_f(acc[s]);
    }
    __syncthreads();
    {
        const int o = t;
        float acc[16];
        const float b = h2_b[o];
        #pragma unroll
        for (int s=0;s<16;s++) acc[s]=b;
        const float4* wr = (const float4*)(h2_w + o*128);
        for (int k4=0;k4<32;k4++){
            const float4 wv4 = wr[k4];
            #pragma unroll
            for (int s=0;s<16;s++){
                const float4 vv = *(const float4*)&x1s[s][k4*4];
                acc[s] += wv4.x*vv.x + wv4.y*vv.y + wv4.z*vv.z + wv4.w*vv.w;
            }
        }
        #pragma unroll
        for (int s=0;s<16;s++) x2s[s][o] = gelu_f(acc[s]);
    }
    __syncthreads();
    if (t < 48){
        const int j = t>>4, s = t&15;
        float a = h3_b[j];
        const float* wr = h3_w + j*128;
        for (int k=0;k<128;k++) a += x2s[s][k]*wr[k];
        o3s[s][j] = a;
    }
    __syncthreads();
    if (t < 16){
        const int s = t, n = n0 + s;
        const float dx = o3s[s][0], dy = o3s[s][1];
        float ls = o3s[s][2];
        ls = ls < -6.f ? -6.f : (ls > 3.f ? 3.f : ls);
        const float s0 = p2s[n*4+0]*dx + p2s[n*4+1]*dy;
        const float s1 = p2s[n*4+2]*dx + p2s[n*4+3]*dy;
        const float conf = 1.0f/fmaxf(expf(ls), 1e-4f);
        out[2*n]   = s0;
        out[2*n+1] = s1;
        out[2*N+n] = dx;
        out[3*N+n] = dy;
        out[4*N+n] = ls;
        out[5*N+n] = conf;
    }
}

extern "C" void kernel_launch(void* const* d_in, const int* in_sizes, int n_in,
                              void* d_out, int out_size, void* d_ws, size_t ws_size,
                              hipStream_t stream)
{
    (void)n_in; (void)out_size;
    const float* bottleneck = (const float*)d_in[0];
    const float* vis        = (const float*)d_in[1];
    const float* pos        = (const float*)d_in[2];
    const float* p2s        = (const float*)d_in[3];
    const float* dw_w  = (const float*)d_in[8];
    const float* dw_b  = (const float*)d_in[9];
    const float* ln_g  = (const float*)d_in[10];
    const float* ln_b  = (const float*)d_in[11];
    const float* pw1_w = (const float*)d_in[12];
    const float* pw1_b = (const float*)d_in[13];
    const float* pw2_w = (const float*)d_in[14];
    const float* pw2_b = (const float*)d_in[15];
    const float* gam   = (const float*)d_in[16];
    const float* b1w   = (const float*)d_in[17];
    const float* b1b   = (const float*)d_in[18];
    const float* s1w   = (const float*)d_in[19];
    const float* s1b   = (const float*)d_in[20];
    const float* s2w   = (const float*)d_in[21];
    const float* s2b   = (const float*)d_in[22];
    const float* h1w   = (const float*)d_in[23];
    const float* h1b   = (const float*)d_in[24];
    const float* h2w   = (const float*)d_in[25];
    const float* h2b   = (const float*)d_in[26];
    const float* h3w   = (const float*)d_in[27];
    const float* h3b   = (const float*)d_in[28];

    const int N = in_sizes[2]/2;            // 4096
    float* vec = (float*)d_ws;              // [N][192] f32
    const size_t vec_bytes = (size_t)N*192*sizeof(float);
    unsigned short* Apack = (unsigned short*)((char*)d_ws + vec_bytes);  // stem: 147456 B
    unsigned short* P1 = Apack + 73728;
    unsigned short* P2 = P1 + 262144;
    unsigned short* Pb = P2 + 262144;
    const size_t need = vec_bytes + 147456u + (262144u+262144u+32768u)*2u;

    hipMemsetAsync(d_ws, 0, vec_bytes, stream);

    prepack_kernel<<<36, 256, 0, stream>>>(s1w, s2w, Apack);

    if (ws_size >= need){
        prepack_bn_kernel<<<272, 256, 0, stream>>>(pw1_w, pw2_w, b1w, P1, P2, Pb);
        fused_branches<<<3*(N/2), 512, 0, stream>>>(bottleneck, vis, pos,
                                                    dw_w, dw_b, ln_g, ln_b,
                                                    pw1_b, pw2_b, gam, b1b,
                                                    (const short8*)P1, (const short8*)P2, (const short8*)Pb,
                                                    (const short8*)Apack, s1b, s2b, vec);
    } else {
        bn_branch_valu<<<N, 256, 0, stream>>>(bottleneck, pos, dw_w, dw_b, ln_g, ln_b,
                                              pw1_w, pw1_b, pw2_w, pw2_b, gam, b1w, b1b, vec);
        stem_branch_kernel<<<N, 512, 0, stream>>>(vis, pos, (const short8*)Apack, s1b, s2b, vec);
    }
    head16_kernel<<<N/16, 128, 0, stream>>>(vec, p2s, h1w, h1b, h2w, h2b, h3w, h3b,
                                            (float*)d_out, N);
}

// Round 13
// 776.273 us; speedup vs baseline: 1.1198x; 1.1198x over previous
//
#include <hip/hip_runtime.h>
#include <hip/hip_bf16.h>

#define XSTR 28   // legacy BN VALU kernel stride

typedef short short8 __attribute__((ext_vector_type(8)));
typedef float f32x4  __attribute__((ext_vector_type(4)));
typedef float f32x16 __attribute__((ext_vector_type(16)));

__device__ __forceinline__ float gelu_f(float x){
    return 0.5f*x*(1.0f + erff(x*0.70710678118654752f));
}
__device__ __forceinline__ float gelu_q(float x){
    const float z = 1.5957691216057308f*x*(1.0f + 0.044715f*x*x);
    return x / (1.0f + __expf(-z));
}
__device__ __forceinline__ unsigned short f2bf(float f){
    unsigned int u = __float_as_uint(f);
    u += 0x7fffu + ((u>>16)&1u);
    return (unsigned short)(u>>16);
}
__device__ __forceinline__ unsigned int pack2(float a, float b){
    return (unsigned int)f2bf(a) | ((unsigned int)f2bf(b)<<16);
}
__device__ __forceinline__ float bf_lo(unsigned int u){ return __uint_as_float(u<<16); }
__device__ __forceinline__ float bf_hi(unsigned int u){ return __uint_as_float(u & 0xffff0000u); }
__device__ __forceinline__ float bfu(unsigned short v){ return __uint_as_float(((unsigned int)v)<<16); }

__device__ __forceinline__ void fma_row25(const float* __restrict__ row, float w, float* __restrict__ acc){
    const float4* r4 = (const float4*)row;
    float4 a0=r4[0], a1=r4[1], a2=r4[2], a3=r4[3], a4=r4[4], a5=r4[5];
    float a6 = row[24];
    acc[0]+=a0.x*w;  acc[1]+=a0.y*w;  acc[2]+=a0.z*w;  acc[3]+=a0.w*w;
    acc[4]+=a1.x*w;  acc[5]+=a1.y*w;  acc[6]+=a1.z*w;  acc[7]+=a1.w*w;
    acc[8]+=a2.x*w;  acc[9]+=a2.y*w;  acc[10]+=a2.z*w; acc[11]+=a2.w*w;
    acc[12]+=a3.x*w; acc[13]+=a3.y*w; acc[14]+=a3.z*w; acc[15]+=a3.w*w;
    acc[16]+=a4.x*w; acc[17]+=a4.y*w; acc[18]+=a4.z*w; acc[19]+=a4.w*w;
    acc[20]+=a5.x*w; acc[21]+=a5.y*w; acc[22]+=a5.z*w; acc[23]+=a5.w*w;
    acc[24]+=a6*w;
}

// ================= BN body (proven r7-r12), LDS passed in =================
__device__ __forceinline__ void bn_body(
    unsigned char* __restrict__ U, int n0, int t,
    const float* __restrict__ bottleneck, const float* __restrict__ pos,
    const float* __restrict__ dw_w, const float* __restrict__ dw_b,
    const float* __restrict__ ln_g, const float* __restrict__ ln_b,
    const float* __restrict__ pw1_b, const float* __restrict__ pw2_b,
    const float* __restrict__ cn_gamma, const float* __restrict__ bn1x1_b,
    const short8* __restrict__ P1v, const short8* __restrict__ P2v,
    const short8* __restrict__ Pbv,
    float* __restrict__ vec_out)
{
    unsigned char* Xb = U;
    unsigned char* Hc = U + 32768;
    float* redA = (float*)(U + 49152);
    float* redB = (float*)(U + 50752);
    float* muS  = (float*)(U + 52352);
    float* rsS  = (float*)(U + 52576);

    const int lane = t & 63, w = t >> 6;
    const int mcol = lane & 15, h4 = lane >> 4;
    const int sP = t >> 8, cP = t & 255;

    unsigned int wvp[13];
    float xdw[25];
    {
        const int n = n0 + sP;
        const float px = pos[2*n]*0.125f, py = pos[2*n+1]*0.125f;
        const float fpx = floorf(px), fpy = floorf(py);
        const int ix0 = (int)fpx - 2, iy0 = (int)fpy - 2;
        const float fx = px - fpx, fy = py - fpy;
        const float w00=(1.f-fy)*(1.f-fx), w01=(1.f-fy)*fx, w10=fy*(1.f-fx), w11=fy*fx;
        float wv[25];
        {
            const float* fm = bottleneck + cP*16384;
            float P[6][6];
            #pragma unroll
            for (int r=0;r<6;r++){
                const int y = iy0+r;
                const bool yok = (y>=0)&&(y<128);
                const int yc = y<0?0:(y>127?127:y);
                #pragma unroll
                for (int s=0;s<6;s++){
                    const int x = ix0+s;
                    const bool ok = yok && (x>=0) && (x<128);
                    const int xc = x<0?0:(x>127?127:x);
                    P[r][s] = ok ? fm[yc*128+xc] : 0.f;
                }
            }
            #pragma unroll
            for (int a=0;a<5;a++)
            #pragma unroll
            for (int b=0;b<5;b++)
                wv[a*5+b] = w00*P[a][b]+w01*P[a][b+1]+w10*P[a+1][b]+w11*P[a+1][b+1];
        }
        #pragma unroll
        for (int i=0;i<12;i++) wvp[i] = pack2(wv[2*i], wv[2*i+1]);
        wvp[12] = pack2(wv[24], 0.f);
        {
            float wcr[49];
            const float* wc = dw_w + cP*49;
            #pragma unroll
            for (int k=0;k<49;k++) wcr[k]=wc[k];
            const float bb = dw_b[cP];
            #pragma unroll
            for (int i=0;i<5;i++){
                #pragma unroll
                for (int j=0;j<5;j++){
                    float a = bb;
                    #pragma unroll
                    for (int u=0;u<7;u++){
                        const int y = i+u-3;
                        if (y<0||y>4) continue;
                        #pragma unroll
                        for (int v=0;v<7;v++){
                            const int x = j+v-3;
                            if (x<0||x>4) continue;
                            a += wv[y*5+x]*wcr[u*7+v];
                        }
                    }
                    xdw[i*5+j] = a;
                }
            }
        }
        #pragma unroll
        for (int p=0;p<25;p++){
            const int row = sP*32 + p;
            *(unsigned short*)(Xb + row*512 + ((2*cP) ^ ((row&7)<<4))) = f2bf(xdw[p]);
        }
    }
    __syncthreads();
    if (t < 400){
        const int sp = t>>3, part = t&7;
        const int row = (sp/25)*32 + (sp - (sp/25)*25);
        float a=0.f, b=0.f;
        for (int c=part; c<256; c+=8){
            const float v = bfu(*(const unsigned short*)(Xb + row*512 + ((2*c) ^ ((row&7)<<4))));
            a += v; b += v*v;
        }
        redA[t]=a; redB[t]=b;
    }
    __syncthreads();
    if (t < 50){
        float a=0.f, b=0.f;
        #pragma unroll
        for (int s=0;s<8;s++){ a+=redA[t*8+s]; b+=redB[t*8+s]; }
        const float m = a*(1.f/256.f);
        const float var = b*(1.f/256.f) - m*m;
        muS[t]=m; rsS[t]=rsqrtf(var+1e-6f);
    }
    __syncthreads();
    {
        const float g = ln_g[cP], bb = ln_b[cP];
        #pragma unroll
        for (int p=0;p<25;p++){
            const int row = sP*32 + p;
            const float v = (xdw[p]-muS[sP*25+p])*rsS[sP*25+p]*g + bb;
            *(unsigned short*)(Xb + row*512 + ((2*cP) ^ ((row&7)<<4))) = f2bf(v);
        }
    }
    __syncthreads();

    f32x4 acc2[2][4];
    #pragma unroll
    for (int ml=0;ml<2;ml++)
        #pragma unroll
        for (int nt=0;nt<4;nt++) acc2[ml][nt]=0.f;

    for (int ch=0; ch<8; ++ch){
        const int mt = ch*8 + w;
        f32x4 a1[4];
        #pragma unroll
        for (int nt=0;nt<4;nt++) a1[nt]=0.f;
        #pragma unroll
        for (int kk=0; kk<8; ++kk){
            const short8 av = P1v[((mt<<3)+kk)*64 + lane];
            #pragma unroll
            for (int nt=0; nt<4; ++nt){
                const int row = nt*16 + mcol;
                const int ad = row*512 + ((kk*64 + h4*16) ^ ((row&7)<<4));
                const short8 bv = *(const short8*)(Xb + ad);
                a1[nt] = __builtin_amdgcn_mfma_f32_16x16x32_bf16(av, bv, a1[nt], 0,0,0);
            }
        }
        {
            const float4 b1v = *(const float4*)(pw1_b + mt*16 + h4*4);
            #pragma unroll
            for (int nt=0; nt<4; ++nt){
                const int row = nt*16 + mcol;
                const float g0 = gelu_q(a1[nt].x + b1v.x);
                const float g1 = gelu_q(a1[nt].y + b1v.y);
                const float g2 = gelu_q(a1[nt].z + b1v.z);
                const float g3 = gelu_q(a1[nt].w + b1v.w);
                const int ad = row*256 + ((w*32 + h4*8) ^ ((row&7)<<4));
                *(uint2*)(Hc + ad) = make_uint2(pack2(g0,g1), pack2(g2,g3));
            }
        }
        __syncthreads();
        #pragma unroll
        for (int ml=0; ml<2; ++ml){
            const int mtc = w*2 + ml;
            #pragma unroll
            for (int kk2=0; kk2<4; ++kk2){
                const short8 av = P2v[(mtc*32 + (ch*4 + kk2))*64 + lane];
                #pragma unroll
                for (int nt=0; nt<4; ++nt){
                    const int row = nt*16 + mcol;
                    const int ad = row*256 + ((kk2*64 + h4*16) ^ ((row&7)<<4));
                    const short8 bv = *(const short8*)(Hc + ad);
                    acc2[ml][nt] = __builtin_amdgcn_mfma_f32_16x16x32_bf16(av, bv, acc2[ml][nt], 0,0,0);
                }
            }
        }
        __syncthreads();
    }

    #pragma unroll
    for (int ml=0; ml<2; ++ml){
        const int c0 = (w*2+ml)*16 + h4*4;
        const float4 gm = *(const float4*)(cn_gamma + c0);
        const float4 b2 = *(const float4*)(pw2_b + c0);
        #pragma unroll
        for (int nt=0; nt<4; ++nt){
            const int row = nt*16 + mcol;
            const int ad = row*512 + ((2*c0) ^ ((row&7)<<4));
            const float f0 = gm.x*(acc2[ml][nt].x + b2.x);
            const float f1 = gm.y*(acc2[ml][nt].y + b2.y);
            const float f2 = gm.z*(acc2[ml][nt].z + b2.z);
            const float f3 = gm.w*(acc2[ml][nt].w + b2.w);
            *(uint2*)(Xb + ad) = make_uint2(pack2(f0,f1), pack2(f2,f3));
        }
    }
    __syncthreads();
    #pragma unroll
    for (int p=0;p<25;p++){
        const int row = sP*32 + p;
        unsigned short* ptr = (unsigned short*)(Xb + row*512 + ((2*cP) ^ ((row&7)<<4)));
        const float r = (p&1) ? bf_hi(wvp[p>>1]) : bf_lo(wvp[p>>1]);
        *ptr = f2bf(bfu(*ptr) + r);
    }
    __syncthreads();

    {
        f32x4 a3[4];
        #pragma unroll
        for (int nt=0;nt<4;nt++) a3[nt]=0.f;
        #pragma unroll
        for (int kk=0; kk<8; ++kk){
            const short8 av = Pbv[((w<<3)+kk)*64 + lane];
            #pragma unroll
            for (int nt=0; nt<4; ++nt){
                const int row = nt*16 + mcol;
                const int ad = row*512 + ((kk*64 + h4*16) ^ ((row&7)<<4));
                const short8 bv = *(const short8*)(Xb + ad);
                a3[nt] = __builtin_amdgcn_mfma_f32_16x16x32_bf16(av, bv, a3[nt], 0,0,0);
            }
        }
        const float4 bb = *(const float4*)(bn1x1_b + w*16 + h4*4);
        float e5[5];
        #pragma unroll
        for (int a=0;a<5;a++){
            const float ta = -1.f + 0.5f*a;
            e5[a] = expf(-3.125f*ta*ta);
        }
        const float Sv = e5[0]+e5[1]+e5[2]+e5[3]+e5[4];
        const float invS = 1.0f/(Sv*Sv);
        float sA[2][4];
        #pragma unroll
        for (int s=0;s<2;s++)
            #pragma unroll
            for (int j=0;j<4;j++) sA[s][j]=0.f;
        #pragma unroll
        for (int nt=0; nt<4; ++nt){
            const int row = nt*16 + mcol;
            const int s = row>>5, p = row&31;
            if (p < 25){
                const int pa = p/5, pb = p - pa*5;
                const float g = e5[pa]*e5[pb];
                sA[s][0] += g*gelu_q(a3[nt].x + bb.x);
                sA[s][1] += g*gelu_q(a3[nt].y + bb.y);
                sA[s][2] += g*gelu_q(a3[nt].z + bb.z);
                sA[s][3] += g*gelu_q(a3[nt].w + bb.w);
            }
        }
        #pragma unroll
        for (int off=1; off<16; off<<=1){
            #pragma unroll
            for (int s=0;s<2;s++)
                #pragma unroll
                for (int j=0;j<4;j++) sA[s][j] += __shfl_xor(sA[s][j], off);
        }
        if (mcol == 0){
            const int o = w*16 + h4*4;
            #pragma unroll
            for (int s=0;s<2;s++){
                float* vo = vec_out + (n0+s)*192 + o;
                vo[0]=sA[s][0]*invS; vo[1]=sA[s][1]*invS;
                vo[2]=sA[s][2]*invS; vo[3]=sA[s][3]*invS;
            }
        }
    }
}

__global__ __launch_bounds__(512,4) void bn_branch_mfma(
    const float* __restrict__ bottleneck, const float* __restrict__ pos,
    const float* __restrict__ dw_w, const float* __restrict__ dw_b,
    const float* __restrict__ ln_g, const float* __restrict__ ln_b,
    const float* __restrict__ pw1_b, const float* __restrict__ pw2_b,
    const float* __restrict__ cn_gamma, const float* __restrict__ bn1x1_b,
    const short8* __restrict__ P1v, const short8* __restrict__ P2v,
    const short8* __restrict__ Pbv,
    float* __restrict__ vec_out)
{
    __shared__ __align__(16) unsigned char U[52800];
    bn_body(U, blockIdx.x*2, threadIdx.x, bottleneck, pos, dw_w, dw_b, ln_g, ln_b,
            pw1_b, pw2_b, cn_gamma, bn1x1_b, P1v, P2v, Pbv, vec_out);
}

// ---- bn weight prepack (proven) ----
__global__ __launch_bounds__(256) void prepack_bn_kernel(
    const float* __restrict__ W1, const float* __restrict__ W2, const float* __restrict__ Wb,
    unsigned short* __restrict__ P1, unsigned short* __restrict__ P2, unsigned short* __restrict__ Pb)
{
    const int tid = blockIdx.x*256 + threadIdx.x;
    const float* src; unsigned short* dst; int row, col, stride, idx;
    if (tid < 32768){
        idx = tid;
        const int frag = idx>>6, l = idx&63;
        row = (frag>>3)*16 + (l&15); col = (frag&7)*32 + (l>>4)*8; stride = 256;
        src = W1; dst = P1;
    } else if (tid < 65536){
        idx = tid - 32768;
        const int frag = idx>>6, l = idx&63;
        row = (frag>>5)*16 + (l&15); col = (frag&31)*32 + (l>>4)*8; stride = 1024;
        src = W2; dst = P2;
    } else if (tid < 69632){
        idx = tid - 65536;
        const int frag = idx>>6, l = idx&63;
        row = (frag>>3)*16 + (l&15); col = (frag&7)*32 + (l>>4)*8; stride = 256;
        src = Wb; dst = Pb;
    } else return;
    const float* s = src + row*stride + col;
    unsigned int v[4];
    #pragma unroll
    for (int j=0;j<4;j++) v[j] = pack2(s[2*j], s[2*j+1]);
    *(uint4*)(dst + (size_t)idx*8) = make_uint4(v[0],v[1],v[2],v[3]);
}

// ================= BN branch, VALU fallback (proven) =================
__global__ __launch_bounds__(256,2) void bn_branch_valu(
    const float* __restrict__ bottleneck, const float* __restrict__ pos,
    const float* __restrict__ dw_w, const float* __restrict__ dw_b,
    const float* __restrict__ ln_g, const float* __restrict__ ln_b,
    const float* __restrict__ pw1_w, const float* __restrict__ pw1_b,
    const float* __restrict__ pw2_w, const float* __restrict__ pw2_b,
    const float* __restrict__ cn_gamma,
    const float* __restrict__ bn1x1_w, const float* __restrict__ bn1x1_b,
    float* __restrict__ vec_out)
{
    __shared__ float xln[256*XSTR];
    __shared__ float hbuf[256*XSTR];
    __shared__ float redA[200], redB[200];
    __shared__ float mu[25], rs[25];

    const int n = blockIdx.x;
    const int t = threadIdx.x;
    const int c = t;

    const float px = pos[2*n]*0.125f, py = pos[2*n+1]*0.125f;
    const float fpx = floorf(px), fpy = floorf(py);
    const int ix0 = (int)fpx - 2, iy0 = (int)fpy - 2;
    const float fx = px - fpx, fy = py - fpy;
    const float w00=(1.f-fy)*(1.f-fx), w01=(1.f-fy)*fx, w10=fy*(1.f-fx), w11=fy*fx;

    float wv[25];
    {
        const float* fm = bottleneck + c*16384;
        float P[6][6];
        #pragma unroll
        for (int r=0;r<6;r++){
            const int y = iy0+r;
            const bool yok = (y>=0)&&(y<128);
            const int yc = y<0?0:(y>127?127:y);
            #pragma unroll
            for (int s=0;s<6;s++){
                const int x = ix0+s;
                const bool ok = yok && (x>=0) && (x<128);
                const int xc = x<0?0:(x>127?127:x);
                P[r][s] = ok ? fm[yc*128+xc] : 0.f;
            }
        }
        #pragma unroll
        for (int a=0;a<5;a++)
        #pragma unroll
        for (int b=0;b<5;b++)
            wv[a*5+b] = w00*P[a][b]+w01*P[a][b+1]+w10*P[a+1][b]+w11*P[a+1][b+1];
    }
    {
        float wcr[49];
        const float* wc = dw_w + c*49;
        #pragma unroll
        for (int k=0;k<49;k++) wcr[k]=wc[k];
        const float bb = dw_b[c];
        #pragma unroll
        for (int i=0;i<5;i++){
            #pragma unroll
            for (int j=0;j<5;j++){
                float a = bb;
                #pragma unroll
                for (int u=0;u<7;u++){
                    const int y = i+u-3;
                    if (y<0||y>4) continue;
                    #pragma unroll
                    for (int v=0;v<7;v++){
                        const int x = j+v-3;
                        if (x<0||x>4) continue;
                        a += wv[y*5+x]*wcr[u*7+v];
                    }
                }
                xln[c*XSTR + i*5+j] = a;
            }
        }
    }
    __syncthreads();
    if (t < 200){
        const int p = t>>3, s = t&7;
        float a=0.f, b=0.f;
        for (int cc=s; cc<256; cc+=8){
            const float v = xln[cc*XSTR+p];
            a += v; b += v*v;
        }
        redA[t]=a; redB[t]=b;
    }
    __syncthreads();
    if (t < 25){
        float a=0.f, b=0.f;
        #pragma unroll
        for (int s=0;s<8;s++){ a+=redA[t*8+s]; b+=redB[t*8+s]; }
        const float m = a*(1.f/256.f);
        const float var = b*(1.f/256.f) - m*m;
        mu[t]=m; rs[t]=rsqrtf(var+1e-6f);
    }
    __syncthreads();
    {
        const float g = ln_g[c], bb = ln_b[c];
        #pragma unroll
        for (int p=0;p<25;p++)
            xln[c*XSTR+p] = (xln[c*XSTR+p]-mu[p])*rs[p]*g + bb;
    }
    __syncthreads();
    float acc2[25];
    #pragma unroll
    for (int p=0;p<25;p++) acc2[p]=0.f;
    for (int r=0;r<4;r++){
        const int o = r*256 + t;
        float h[25];
        {
            const float b1 = pw1_b[o];
            #pragma unroll
            for (int p=0;p<25;p++) h[p]=b1;
            const float* wr = pw1_w + o*256;
            for (int cc=0;cc<256;cc++)
                fma_row25(xln + cc*XSTR, wr[cc], h);
            #pragma unroll
            for (int p=0;p<25;p++) h[p]=gelu_f(h[p]);
        }
        __syncthreads();
        #pragma unroll
        for (int p=0;p<25;p++) hbuf[t*XSTR+p]=h[p];
        __syncthreads();
        {
            const float* w2 = pw2_w + t*1024 + r*256;
            for (int k=0;k<256;k++)
                fma_row25(hbuf + k*XSTR, w2[k], acc2);
        }
    }
    {
        const float gam = cn_gamma[c], b2 = pw2_b[c];
        #pragma unroll
        for (int p=0;p<25;p++)
            xln[c*XSTR+p] = wv[p] + gam*(acc2[p]+b2);
    }
    __syncthreads();
    if (t < 128){
        float acc[25];
        #pragma unroll
        for (int p=0;p<25;p++) acc[p]=0.f;
        const float* wr = bn1x1_w + t*256;
        for (int cc=0;cc<256;cc++)
            fma_row25(xln + cc*XSTR, wr[cc], acc);
        const float b = bn1x1_b[t];
        float e5[5];
        #pragma unroll
        for (int a=0;a<5;a++){
            const float ta = -1.f + 0.5f*a;
            e5[a] = expf(-3.125f*ta*ta);
        }
        const float Sv = e5[0]+e5[1]+e5[2]+e5[3]+e5[4];
        float res = 0.f;
        #pragma unroll
        for (int a=0;a<5;a++){
            float rowa = 0.f;
            #pragma unroll
            for (int bb=0;bb<5;bb++)
                rowa += e5[bb]*gelu_f(acc[a*5+bb]+b);
            res += e5[a]*rowa;
        }
        vec_out[n*192+t] = res/(Sv*Sv);
    }
}

// ---------------- Stem weight prepack: 32x32x16 A-fragment layout (proven r9) ----------------
__global__ __launch_bounds__(256) void prepack_kernel(
    const float* __restrict__ W1, const float* __restrict__ W2,
    unsigned short* __restrict__ Ap)
{
    const int tid = blockIdx.x*256 + threadIdx.x;
    if (tid >= 9216) return;
    const int conv = tid / 4608;
    const int r = tid - conv*4608;
    const int frag = r >> 6, l = r & 63;
    const int k  = frag >> 3;
    const int kt = (frag >> 1) & 3;
    const int wo = frag & 1;
    const float* W = conv ? W2 : W1;
    const int o  = wo*32 + (l & 31);
    const int c0 = kt*16 + (l >> 5)*8;
    unsigned int v[4];
    #pragma unroll
    for (int jj=0; jj<4; jj++){
        const float f0 = W[o*576 + (c0+2*jj  )*9 + k];
        const float f1 = W[o*576 + (c0+2*jj+1)*9 + k];
        v[jj] = pack2(f0, f1);
    }
    *(uint4*)(Ap + (size_t)tid*8) = make_uint4(v[0], v[1], v[2], v[3]);
}

// ---------------- vis transpose: [64][1024][1024] f32 -> [1024][1024][64] bf16 ----------------
__global__ __launch_bounds__(256) void transpose_vis_kernel(
    const float* __restrict__ vis, unsigned short* __restrict__ visT)
{
    __shared__ unsigned short T[64*66];   // [c][x], stride 66 shorts -> conflict-free row reads
    const int b = blockIdx.x;
    const int y = b >> 4, x0 = (b & 15) << 6;
    const int t = threadIdx.x, lane = t & 63, w = t >> 6;
    #pragma unroll
    for (int i = 0; i < 16; ++i){
        const int c = w*16 + i;
        T[c*66 + lane] = f2bf(vis[c*1048576 + y*1024 + x0 + lane]);
    }
    __syncthreads();
    const int x = t >> 2, cg0 = (t & 3) * 16;
    #pragma unroll
    for (int h = 0; h < 2; ++h){
        const int cg = cg0 + h*8;
        unsigned int v[4];
        #pragma unroll
        for (int j = 0; j < 4; ++j){
            const unsigned int a = T[(cg + 2*j    )*66 + x];
            const unsigned int bsh = T[(cg + 2*j + 1)*66 + x];
            v[j] = a | (bsh << 16);
        }
        *(uint4*)(visT + ((size_t)(y*1024) + x0 + x)*64 + cg) = make_uint4(v[0],v[1],v[2],v[3]);
    }
}

// ================= Stem body (proven convs r9-r12); gather templated =================
#define STEM_CONV32(SRC, AP)                                                        \
    _Pragma("unroll")                                                               \
    for (int k=0;k<9;k++){                                                          \
        int tj[3];                                                                  \
        _Pragma("unroll")                                                           \
        for (int j=0;j<3;j++)                                                       \
            tj[j] = (int)sTab[m*90 + (j<cnt ? st+j : st)*9 + k];                    \
        _Pragma("unroll")                                                           \
        for (int kt=0;kt<4;kt++){                                                   \
            const short8 av = (AP)[(k*8 + kt*2 + wo)*64 + lane];                    \
            const int cb = kt*32 + hi16;                                            \
            _Pragma("unroll")                                                       \
            for (int j=0;j<3;j++){                                                  \
                if (j < cnt){                                                       \
                    const short8 bv = *(const short8*)((SRC) + (tj[j] ^ cb));       \
                    acc[j] = __builtin_amdgcn_mfma_f32_32x32x16_bf16(av, bv, acc[j], 0,0,0); \
                }                                                                   \
            }                                                                       \
        }                                                                           \
    }

template<bool TR>
__device__ __forceinline__ void stem_body(
    unsigned char* __restrict__ U, int n, int t,
    const float* __restrict__ vis, const unsigned short* __restrict__ visT,
    const float* __restrict__ pos,
    const short8* __restrict__ Ap1,
    const float* __restrict__ st1_b, const float* __restrict__ st2_b,
    float* __restrict__ vec_out)
{
    unsigned char* sXt = U;                                  // 37120
    unsigned short* sTab = (unsigned short*)(U + 37120);     // 5760
    float (*redS)[4] = (float(*)[4])(U + 42880);             // 1024 -> 43904

    const int lane = t & 63;
    const int m = lane & 31;
    const int hi = lane >> 5;
    const int hi16 = hi*16;
    const int w = t >> 6;
    const int wo = w & 1;
    const int nh = w >> 1;
    const int st  = nh*3 - (nh==3 ? 1 : 0);
    const int cnt = (nh < 2) ? 3 : 2;

    const float fpx0 = pos[2*n], fpy0 = pos[2*n+1];
    const float fpx = floorf(fpx0), fpy = floorf(fpy0);
    const int ix0 = (int)fpx - 8, iy0 = (int)fpy - 8;
    const float fx = fpx0-fpx, fy = fpy0-fpy;
    const float w00=(1.f-fy)*(1.f-fx), w01=(1.f-fy)*fx, w10=fy*(1.f-fx), w11=fy*fx;

    if (t < 32) *(unsigned int*)(sXt + 289*128 + t*4) = 0u;

    for (int idx = t; idx < 32*90; idx += 512){
        const int mm = idx/90, rem = idx - mm*90;
        const int nt = rem/9, k = rem - nt*9;
        const int p = nt*32 + mm;
        int pp = 289;
        if (p < 289){
            const int py = (p*241)>>12, px = p - py*17;
            const int y = py + k/3 - 1, x = px + (k - (k/3)*3) - 1;
            if (((unsigned)y < 17u) && ((unsigned)x < 17u)) pp = y*17 + x;
        }
        sTab[idx] = (unsigned short)(pp*128 + ((pp&7)<<4));
    }

    if (TR){
        // coalesced gather from channel-last bf16 visT: 128B per pixel
        for (int idx = t; idx < 289*8; idx += 512){
            const int p = idx >> 3, cg = (idx & 7) * 8;
            const int py = (p*241)>>12, px = p - py*17;
            const unsigned short* q = visT + (size_t)((iy0+py)*1024 + (ix0+px))*64 + cg;
            const uint4 q00 = *(const uint4*)(q);
            const uint4 q01 = *(const uint4*)(q + 64);
            const uint4 q10 = *(const uint4*)(q + 65536);
            const uint4 q11 = *(const uint4*)(q + 65536 + 64);
            unsigned int o[4];
            #pragma unroll
            for (int j=0;j<4;j++){
                const unsigned int u00=((const unsigned int*)&q00)[j];
                const unsigned int u01=((const unsigned int*)&q01)[j];
                const unsigned int u10=((const unsigned int*)&q10)[j];
                const unsigned int u11=((const unsigned int*)&q11)[j];
                const float lo = bf_lo(u00)*w00 + bf_lo(u01)*w01 + bf_lo(u10)*w10 + bf_lo(u11)*w11;
                const float hv = bf_hi(u00)*w00 + bf_hi(u01)*w01 + bf_hi(u10)*w10 + bf_hi(u11)*w11;
                o[j] = pack2(lo, hv);
            }
            *(uint4*)(sXt + p*128 + ((2*cg) ^ ((p&7)<<4))) = make_uint4(o[0],o[1],o[2],o[3]);
        }
    } else {
        for (int task = t; task < 64*17; task += 512){
            const int c  = task & 63;
            const int py = task >> 6;
            const float* r0 = vis + c*1048576 + (iy0+py)*1024 + ix0;
            float a[18], b[18];
            #pragma unroll
            for (int kk=0; kk<18; kk++){ a[kk]=r0[kk]; b[kk]=r0[1024+kk]; }
            #pragma unroll
            for (int px=0; px<17; px++){
                const float v = w00*a[px] + w01*a[px+1] + w10*b[px] + w11*b[px+1];
                const int p = py*17 + px;
                *(unsigned short*)(sXt + p*128 + ((2*c) ^ ((p&7)<<4))) = f2bf(v);
            }
        }
    }
    __syncthreads();

    f32x16 acc[3];
    #pragma unroll
    for (int j=0;j<3;j++) acc[j] = 0.f;
    STEM_CONV32(sXt, Ap1)

    uint2 pk[3][4];
    {
        float4 b4[4];
        #pragma unroll
        for (int rg=0;rg<4;rg++) b4[rg] = *(const float4*)(st1_b + wo*32 + 8*rg + 4*hi);
        #pragma unroll
        for (int j=0;j<3;j++){
            if (j < cnt){
                #pragma unroll
                for (int rg=0;rg<4;rg++){
                    const float v0 = gelu_q(acc[j][4*rg+0] + b4[rg].x);
                    const float v1 = gelu_q(acc[j][4*rg+1] + b4[rg].y);
                    const float v2 = gelu_q(acc[j][4*rg+2] + b4[rg].z);
                    const float v3 = gelu_q(acc[j][4*rg+3] + b4[rg].w);
                    pk[j][rg] = make_uint2(pack2(v0,v1), pack2(v2,v3));
                }
            }
        }
    }
    __syncthreads();

    #pragma unroll
    for (int j=0;j<3;j++){
        if (j < cnt){
            const int p = (st+j)*32 + m;
            if (p < 289){
                const int swz = (p&7)<<4;
                #pragma unroll
                for (int rg=0;rg<4;rg++){
                    const int ch0 = wo*32 + 8*rg + 4*hi;
                    *(uint2*)(sXt + p*128 + ((2*ch0) ^ swz)) = pk[j][rg];
                }
            }
        }
    }
    __syncthreads();

    const short8* Ap2 = Ap1 + 4608;
    #pragma unroll
    for (int j=0;j<3;j++) acc[j] = 0.f;
    STEM_CONV32(sXt, Ap2)

    {
        float4 b4[4];
        #pragma unroll
        for (int rg=0;rg<4;rg++) b4[rg] = *(const float4*)(st2_b + wo*32 + 8*rg + 4*hi);
        float s[16];
        #pragma unroll
        for (int r=0;r<16;r++) s[r]=0.f;
        #pragma unroll
        for (int j=0;j<3;j++){
            if (j < cnt){
                const int p = (st+j)*32 + m;
                if (p < 289){
                    const int py = (p*241)>>12;
                    const int px = p - py*17;
                    const float ty = -1.f + 0.125f*py;
                    const float tx = -1.f + 0.125f*px;
                    const float g = expf(-3.125f*(ty*ty + tx*tx));
                    #pragma unroll
                    for (int rg=0;rg<4;rg++){
                        s[4*rg+0] += g*gelu_q(acc[j][4*rg+0] + b4[rg].x);
                        s[4*rg+1] += g*gelu_q(acc[j][4*rg+1] + b4[rg].y);
                        s[4*rg+2] += g*gelu_q(acc[j][4*rg+2] + b4[rg].z);
                        s[4*rg+3] += g*gelu_q(acc[j][4*rg+3] + b4[rg].w);
                    }
                }
            }
        }
        #pragma unroll
        for (int off=1; off<32; off<<=1){
            #pragma unroll
            for (int r=0;r<16;r++) s[r] += __shfl_xor(s[r], off);
        }
        if (m == 0){
            #pragma unroll
            for (int rg=0;rg<4;rg++)
                #pragma unroll
                for (int e=0;e<4;e++)
                    redS[wo*32 + 8*rg + 4*hi + e][nh] = s[4*rg+e];
        }
    }
    __syncthreads();
    if (t < 64){
        float Sv = 0.f;
        #pragma unroll
        for (int j=0;j<17;j++){
            const float tj = -1.f + 0.125f*j;
            Sv += expf(-3.125f*tj*tj);
        }
        vec_out[n*192+128+t] = (redS[t][0] + redS[t][1] + redS[t][2] + redS[t][3]) / (Sv*Sv);
    }
}

__global__ __launch_bounds__(512,4) void stem_kernel_tr(
    const unsigned short* __restrict__ visT, const float* __restrict__ pos,
    const short8* __restrict__ Ap1,
    const float* __restrict__ st1_b, const float* __restrict__ st2_b,
    float* __restrict__ vec_out)
{
    __shared__ __align__(16) unsigned char U[43904];
    stem_body<true>(U, blockIdx.x, threadIdx.x, nullptr, visT, pos, Ap1, st1_b, st2_b, vec_out);
}

__global__ __launch_bounds__(512,4) void stem_branch_kernel(
    const float* __restrict__ vis, const float* __restrict__ pos,
    const short8* __restrict__ Ap1,
    const float* __restrict__ st1_b, const float* __restrict__ st2_b,
    float* __restrict__ vec_out)
{
    __shared__ __align__(16) unsigned char U[43904];
    stem_body<false>(U, blockIdx.x, threadIdx.x, vis, nullptr, pos, Ap1, st1_b, st2_b, vec_out);
}

// ---------------- Head: 16 samples/block (proven) ----------------
__global__ __launch_bounds__(128) void head16_kernel(
    const float* __restrict__ vec, const float* __restrict__ p2s,
    const float* __restrict__ h1_w, const float* __restrict__ h1_b,
    const float* __restrict__ h2_w, const float* __restrict__ h2_b,
    const float* __restrict__ h3_w, const float* __restrict__ h3_b,
    float* __restrict__ out, int N)
{
    __shared__ float v[16][192];
    __shared__ float x1s[16][132];
    __shared__ float x2s[16][132];
    __shared__ float o3s[16][4];
    const int n0 = blockIdx.x*16, t = threadIdx.x;

    for (int idx=t; idx<16*192; idx+=128){
        const int s = idx/192, k = idx - s*192;
        v[s][k] = vec[n0*192 + idx];
    }
    __syncthreads();
    {
        const int o = t;
        float acc[16];
        const float b = h1_b[o];
        #pragma unroll
        for (int s=0;s<16;s++) acc[s]=b;
        const float4* wr = (const float4*)(h1_w + o*192);
        for (int k4=0;k4<48;k4++){
            const float4 wv4 = wr[k4];
            #pragma unroll
            for (int s=0;s<16;s++){
                const float4 vv = *(const float4*)&v[s][k4*4];
                acc[s] += wv4.x*vv.x + wv4.y*vv.y + wv4.z*vv.z + wv4.w*vv.w;
            }
        }
        #pragma unroll
        for (int s=0;s<16;s++) x1s[s][o] = gelu_f(acc[s]);
    }
    __syncthreads();
    {
        const int o = t;
        float acc[16];
        const float b = h2_b[o];
        #pragma unroll
        for (int s=0;s<16;s++) acc[s]=b;
        const float4* wr = (const float4*)(h2_w + o*128);
        for (int k4=0;k4<32;k4++){
            const float4 wv4 = wr[k4];
            #pragma unroll
            for (int s=0;s<16;s++){
                const float4 vv = *(const float4*)&x1s[s][k4*4];
                acc[s] += wv4.x*vv.x + wv4.y*vv.y + wv4.z*vv.z + wv4.w*vv.w;
            }
        }
        #pragma unroll
        for (int s=0;s<16;s++) x2s[s][o] = gelu_f(acc[s]);
    }
    __syncthreads();
    if (t < 48){
        const int j = t>>4, s = t&15;
        float a = h3_b[j];
        const float* wr = h3_w + j*128;
        for (int k=0;k<128;k++) a += x2s[s][k]*wr[k];
        o3s[s][j] = a;
    }
    __syncthreads();
    if (t < 16){
        const int s = t, n = n0 + s;
        const float dx = o3s[s][0], dy = o3s[s][1];
        float ls = o3s[s][2];
        ls = ls < -6.f ? -6.f : (ls > 3.f ? 3.f : ls);
        const float s0 = p2s[n*4+0]*dx + p2s[n*4+1]*dy;
        const float s1 = p2s[n*4+2]*dx + p2s[n*4+3]*dy;
        const float conf = 1.0f/fmaxf(expf(ls), 1e-4f);
        out[2*n]   = s0;
        out[2*n+1] = s1;
        out[2*N+n] = dx;
        out[3*N+n] = dy;
        out[4*N+n] = ls;
        out[5*N+n] = conf;
    }
}

extern "C" void kernel_launch(void* const* d_in, const int* in_sizes, int n_in,
                              void* d_out, int out_size, void* d_ws, size_t ws_size,
                              hipStream_t stream)
{
    (void)n_in; (void)out_size;
    const float* bottleneck = (const float*)d_in[0];
    const float* vis        = (const float*)d_in[1];
    const float* pos        = (const float*)d_in[2];
    const float* p2s        = (const float*)d_in[3];
    const float* dw_w  = (const float*)d_in[8];
    const float* dw_b  = (const float*)d_in[9];
    const float* ln_g  = (const float*)d_in[10];
    const float* ln_b  = (const float*)d_in[11];
    const float* pw1_w = (const float*)d_in[12];
    const float* pw1_b = (const float*)d_in[13];
    const float* pw2_w = (const float*)d_in[14];
    const float* pw2_b = (const float*)d_in[15];
    const float* gam   = (const float*)d_in[16];
    const float* b1w   = (const float*)d_in[17];
    const float* b1b   = (const float*)d_in[18];
    const float* s1w   = (const float*)d_in[19];
    const float* s1b   = (const float*)d_in[20];
    const float* s2w   = (const float*)d_in[21];
    const float* s2b   = (const float*)d_in[22];
    const float* h1w   = (const float*)d_in[23];
    const float* h1b   = (const float*)d_in[24];
    const float* h2w   = (const float*)d_in[25];
    const float* h2b   = (const float*)d_in[26];
    const float* h3w   = (const float*)d_in[27];
    const float* h3b   = (const float*)d_in[28];

    const int N = in_sizes[2]/2;            // 4096
    char* ws = (char*)d_ws;
    float* vec = (float*)ws;                                  // 3,145,728
    unsigned short* Apack = (unsigned short*)(ws + 3145728);  //   147,456
    unsigned short* P1    = (unsigned short*)(ws + 3293184);  //   524,288
    unsigned short* P2    = (unsigned short*)(ws + 3817472);  //   524,288
    unsigned short* Pb    = (unsigned short*)(ws + 4341760);  //    65,536
    unsigned short* visT  = (unsigned short*)(ws + 4407296);  // 134,217,728
    const size_t need_mfma = 4407296u;
    const size_t need_tr   = 4407296u + 134217728ull;
    const size_t vec_bytes = (size_t)N*192*sizeof(float);

    hipMemsetAsync(d_ws, 0, vec_bytes, stream);
    prepack_kernel<<<36, 256, 0, stream>>>(s1w, s2w, Apack);

    if (ws_size >= need_tr){
        prepack_bn_kernel<<<272, 256, 0, stream>>>(pw1_w, pw2_w, b1w, P1, P2, Pb);
        transpose_vis_kernel<<<16384, 256, 0, stream>>>(vis, visT);
        stem_kernel_tr<<<N, 512, 0, stream>>>(visT, pos, (const short8*)Apack, s1b, s2b, vec);
        bn_branch_mfma<<<N/2, 512, 0, stream>>>(bottleneck, pos, dw_w, dw_b, ln_g, ln_b,
                                                pw1_b, pw2_b, gam, b1b,
                                                (const short8*)P1, (const short8*)P2, (const short8*)Pb,
                                                vec);
    } else if (ws_size >= need_mfma){
        prepack_bn_kernel<<<272, 256, 0, stream>>>(pw1_w, pw2_w, b1w, P1, P2, Pb);
        bn_branch_mfma<<<N/2, 512, 0, stream>>>(bottleneck, pos, dw_w, dw_b, ln_g, ln_b,
                                                pw1_b, pw2_b, gam, b1b,
                                                (const short8*)P1, (const short8*)P2, (const short8*)Pb,
                                                vec);
        stem_branch_kernel<<<N, 512, 0, stream>>>(vis, pos, (const short8*)Apack, s1b, s2b, vec);
    } else {
        bn_branch_valu<<<N, 256, 0, stream>>>(bottleneck, pos, dw_w, dw_b, ln_g, ln_b,
                                              pw1_w, pw1_b, pw2_w, pw2_b, gam, b1w, b1b, vec);
        stem_branch_kernel<<<N, 512, 0, stream>>>(vis, pos, (const short8*)Apack, s1b, s2b, vec);
    }
    head16_kernel<<<N/16, 128, 0, stream>>>(vec, p2s, h1w, h1b, h2w, h2b, h3w, h3b,
                                            (float*)d_out, N);
}

// Round 14
// 739.194 us; speedup vs baseline: 1.1760x; 1.0502x over previous
//
#include <hip/hip_runtime.h>
#include <hip/hip_bf16.h>

#define XSTR 28   // legacy BN VALU kernel stride

typedef short short8 __attribute__((ext_vector_type(8)));
typedef float f32x4  __attribute__((ext_vector_type(4)));
typedef float f32x16 __attribute__((ext_vector_type(16)));

__device__ __forceinline__ float gelu_f(float x){
    return 0.5f*x*(1.0f + erff(x*0.70710678118654752f));
}
__device__ __forceinline__ float gelu_q(float x){
    const float z = 1.5957691216057308f*x*(1.0f + 0.044715f*x*x);
    return x / (1.0f + __expf(-z));
}
__device__ __forceinline__ unsigned short f2bf(float f){
    unsigned int u = __float_as_uint(f);
    u += 0x7fffu + ((u>>16)&1u);
    return (unsigned short)(u>>16);
}
__device__ __forceinline__ unsigned int pack2(float a, float b){
    return (unsigned int)f2bf(a) | ((unsigned int)f2bf(b)<<16);
}
__device__ __forceinline__ float bf_lo(unsigned int u){ return __uint_as_float(u<<16); }
__device__ __forceinline__ float bf_hi(unsigned int u){ return __uint_as_float(u & 0xffff0000u); }
__device__ __forceinline__ float bfu(unsigned short v){ return __uint_as_float(((unsigned int)v)<<16); }

__device__ __forceinline__ void fma_row25(const float* __restrict__ row, float w, float* __restrict__ acc){
    const float4* r4 = (const float4*)row;
    float4 a0=r4[0], a1=r4[1], a2=r4[2], a3=r4[3], a4=r4[4], a5=r4[5];
    float a6 = row[24];
    acc[0]+=a0.x*w;  acc[1]+=a0.y*w;  acc[2]+=a0.z*w;  acc[3]+=a0.w*w;
    acc[4]+=a1.x*w;  acc[5]+=a1.y*w;  acc[6]+=a1.z*w;  acc[7]+=a1.w*w;
    acc[8]+=a2.x*w;  acc[9]+=a2.y*w;  acc[10]+=a2.z*w; acc[11]+=a2.w*w;
    acc[12]+=a3.x*w; acc[13]+=a3.y*w; acc[14]+=a3.z*w; acc[15]+=a3.w*w;
    acc[16]+=a4.x*w; acc[17]+=a4.y*w; acc[18]+=a4.z*w; acc[19]+=a4.w*w;
    acc[20]+=a5.x*w; acc[21]+=a5.y*w; acc[22]+=a5.z*w; acc[23]+=a5.w*w;
    acc[24]+=a6*w;
}

// ================= BN body (r7-r13 proven pipeline; gather templated) =================
template<bool BTR>
__device__ __forceinline__ void bn_body(
    unsigned char* __restrict__ U, int n0, int t,
    const float* __restrict__ bottleneck, const unsigned short* __restrict__ bnT,
    const float* __restrict__ pos,
    const float* __restrict__ dw_w, const float* __restrict__ dw_b,
    const float* __restrict__ ln_g, const float* __restrict__ ln_b,
    const float* __restrict__ pw1_b, const float* __restrict__ pw2_b,
    const float* __restrict__ cn_gamma, const float* __restrict__ bn1x1_b,
    const short8* __restrict__ P1v, const short8* __restrict__ P2v,
    const short8* __restrict__ Pbv,
    float* __restrict__ vec_out)
{
    unsigned char* Xb = U;
    unsigned char* Hc = U + 32768;
    float* redA = (float*)(U + 49152);
    float* redB = (float*)(U + 50752);
    float* muS  = (float*)(U + 52352);
    float* rsS  = (float*)(U + 52576);

    const int lane = t & 63, w = t >> 6;
    const int mcol = lane & 15, h4 = lane >> 4;
    const int sP = t >> 8, cP = t & 255;

    unsigned int wvp[13];

    if (BTR){
        // ---- Phase A: coalesced blend from channel-last bnT into Xb (swizzled) ----
        int ix0A[2], iy0A[2];
        float wbl[2][4];
        #pragma unroll
        for (int s=0;s<2;s++){
            const int n = n0 + s;
            const float px = pos[2*n]*0.125f, py = pos[2*n+1]*0.125f;
            const float fpx = floorf(px), fpy = floorf(py);
            ix0A[s] = (int)fpx - 2; iy0A[s] = (int)fpy - 2;
            const float fx = px - fpx, fy = py - fpy;
            wbl[s][0]=(1.f-fy)*(1.f-fx); wbl[s][1]=(1.f-fy)*fx;
            wbl[s][2]=fy*(1.f-fx);       wbl[s][3]=fy*fx;
        }
        for (int idx = t; idx < 1600; idx += 512){
            const int s = idx/800, rem = idx - s*800;
            const int p = rem >> 5, cg = rem & 31;
            const int a = p/5, bq = p - a*5;
            const int y0 = iy0A[s]+a, x0 = ix0A[s]+bq;
            uint4 q[4];
            #pragma unroll
            for (int e=0;e<4;e++){
                const int yy = y0 + (e>>1), xx = x0 + (e&1);
                const bool ok = ((unsigned)yy < 128u) && ((unsigned)xx < 128u);
                q[e] = ok ? *(const uint4*)(bnT + ((size_t)(yy*128+xx))*256 + cg*8)
                          : make_uint4(0u,0u,0u,0u);
            }
            const float w0=wbl[s][0], w1=wbl[s][1], w2=wbl[s][2], w3=wbl[s][3];
            unsigned int o[4];
            #pragma unroll
            for (int j=0;j<4;j++){
                const unsigned int u0=((const unsigned int*)&q[0])[j];
                const unsigned int u1=((const unsigned int*)&q[1])[j];
                const unsigned int u2=((const unsigned int*)&q[2])[j];
                const unsigned int u3=((const unsigned int*)&q[3])[j];
                const float lo = bf_lo(u0)*w0 + bf_lo(u1)*w1 + bf_lo(u2)*w2 + bf_lo(u3)*w3;
                const float hv = bf_hi(u0)*w0 + bf_hi(u1)*w1 + bf_hi(u2)*w2 + bf_hi(u3)*w3;
                o[j] = pack2(lo, hv);
            }
            const int row = s*32 + p;
            *(uint4*)(Xb + row*512 + ((cg*16) ^ ((row&7)<<4))) = make_uint4(o[0],o[1],o[2],o[3]);
        }
        __syncthreads();
        // ---- Phase B: thread=(s,c) reads its window, packs residual, depthwise, writes xdw ----
        {
            float wv[25];
            #pragma unroll
            for (int p=0;p<25;p++){
                const int row = sP*32 + p;
                wv[p] = bfu(*(const unsigned short*)(Xb + row*512 + ((2*cP) ^ ((row&7)<<4))));
            }
            #pragma unroll
            for (int i=0;i<12;i++) wvp[i] = pack2(wv[2*i], wv[2*i+1]);
            wvp[12] = pack2(wv[24], 0.f);
            float xdw[25];
            {
                float wcr[49];
                const float* wc = dw_w + cP*49;
                #pragma unroll
                for (int k=0;k<49;k++) wcr[k]=wc[k];
                const float bb = dw_b[cP];
                #pragma unroll
                for (int i=0;i<5;i++){
                    #pragma unroll
                    for (int j=0;j<5;j++){
                        float a = bb;
                        #pragma unroll
                        for (int u=0;u<7;u++){
                            const int y = i+u-3;
                            if (y<0||y>4) continue;
                            #pragma unroll
                            for (int v=0;v<7;v++){
                                const int x = j+v-3;
                                if (x<0||x>4) continue;
                                a += wv[y*5+x]*wcr[u*7+v];
                            }
                        }
                        xdw[i*5+j] = a;
                    }
                }
            }
            #pragma unroll
            for (int p=0;p<25;p++){
                const int row = sP*32 + p;
                *(unsigned short*)(Xb + row*512 + ((2*cP) ^ ((row&7)<<4))) = f2bf(xdw[p]);
            }
        }
    } else {
        const int n = n0 + sP;
        const float px = pos[2*n]*0.125f, py = pos[2*n+1]*0.125f;
        const float fpx = floorf(px), fpy = floorf(py);
        const int ix0 = (int)fpx - 2, iy0 = (int)fpy - 2;
        const float fx = px - fpx, fy = py - fpy;
        const float w00=(1.f-fy)*(1.f-fx), w01=(1.f-fy)*fx, w10=fy*(1.f-fx), w11=fy*fx;
        float wv[25];
        {
            const float* fm = bottleneck + cP*16384;
            float P[6][6];
            #pragma unroll
            for (int r=0;r<6;r++){
                const int y = iy0+r;
                const bool yok = (y>=0)&&(y<128);
                const int yc = y<0?0:(y>127?127:y);
                #pragma unroll
                for (int s=0;s<6;s++){
                    const int x = ix0+s;
                    const bool ok = yok && (x>=0) && (x<128);
                    const int xc = x<0?0:(x>127?127:x);
                    P[r][s] = ok ? fm[yc*128+xc] : 0.f;
                }
            }
            #pragma unroll
            for (int a=0;a<5;a++)
            #pragma unroll
            for (int b=0;b<5;b++)
                wv[a*5+b] = w00*P[a][b]+w01*P[a][b+1]+w10*P[a+1][b]+w11*P[a+1][b+1];
        }
        #pragma unroll
        for (int i=0;i<12;i++) wvp[i] = pack2(wv[2*i], wv[2*i+1]);
        wvp[12] = pack2(wv[24], 0.f);
        float xdw[25];
        {
            float wcr[49];
            const float* wc = dw_w + cP*49;
            #pragma unroll
            for (int k=0;k<49;k++) wcr[k]=wc[k];
            const float bb = dw_b[cP];
            #pragma unroll
            for (int i=0;i<5;i++){
                #pragma unroll
                for (int j=0;j<5;j++){
                    float a = bb;
                    #pragma unroll
                    for (int u=0;u<7;u++){
                        const int y = i+u-3;
                        if (y<0||y>4) continue;
                        #pragma unroll
                        for (int v=0;v<7;v++){
                            const int x = j+v-3;
                            if (x<0||x>4) continue;
                            a += wv[y*5+x]*wcr[u*7+v];
                        }
                    }
                    xdw[i*5+j] = a;
                }
            }
        }
        #pragma unroll
        for (int p=0;p<25;p++){
            const int row = sP*32 + p;
            *(unsigned short*)(Xb + row*512 + ((2*cP) ^ ((row&7)<<4))) = f2bf(xdw[p]);
        }
    }
    __syncthreads();
    if (t < 400){
        const int sp = t>>3, part = t&7;
        const int row = (sp/25)*32 + (sp - (sp/25)*25);
        float a=0.f, b=0.f;
        for (int c=part; c<256; c+=8){
            const float v = bfu(*(const unsigned short*)(Xb + row*512 + ((2*c) ^ ((row&7)<<4))));
            a += v; b += v*v;
        }
        redA[t]=a; redB[t]=b;
    }
    __syncthreads();
    if (t < 50){
        float a=0.f, b=0.f;
        #pragma unroll
        for (int s=0;s<8;s++){ a+=redA[t*8+s]; b+=redB[t*8+s]; }
        const float m = a*(1.f/256.f);
        const float var = b*(1.f/256.f) - m*m;
        muS[t]=m; rsS[t]=rsqrtf(var+1e-6f);
    }
    __syncthreads();
    {
        // normalize from LDS (Xb holds xdw), overwrite Xb
        const float g = ln_g[cP], bb = ln_b[cP];
        #pragma unroll
        for (int p=0;p<25;p++){
            const int row = sP*32 + p;
            unsigned short* ptr = (unsigned short*)(Xb + row*512 + ((2*cP) ^ ((row&7)<<4)));
            const float xv = bfu(*ptr);
            *ptr = f2bf((xv-muS[sP*25+p])*rsS[sP*25+p]*g + bb);
        }
    }
    __syncthreads();

    f32x4 acc2[2][4];
    #pragma unroll
    for (int ml=0;ml<2;ml++)
        #pragma unroll
        for (int nt=0;nt<4;nt++) acc2[ml][nt]=0.f;

    for (int ch=0; ch<8; ++ch){
        const int mt = ch*8 + w;
        f32x4 a1[4];
        #pragma unroll
        for (int nt=0;nt<4;nt++) a1[nt]=0.f;
        #pragma unroll
        for (int kk=0; kk<8; ++kk){
            const short8 av = P1v[((mt<<3)+kk)*64 + lane];
            #pragma unroll
            for (int nt=0; nt<4; ++nt){
                const int row = nt*16 + mcol;
                const int ad = row*512 + ((kk*64 + h4*16) ^ ((row&7)<<4));
                const short8 bv = *(const short8*)(Xb + ad);
                a1[nt] = __builtin_amdgcn_mfma_f32_16x16x32_bf16(av, bv, a1[nt], 0,0,0);
            }
        }
        {
            const float4 b1v = *(const float4*)(pw1_b + mt*16 + h4*4);
            #pragma unroll
            for (int nt=0; nt<4; ++nt){
                const int row = nt*16 + mcol;
                const float g0 = gelu_q(a1[nt].x + b1v.x);
                const float g1 = gelu_q(a1[nt].y + b1v.y);
                const float g2 = gelu_q(a1[nt].z + b1v.z);
                const float g3 = gelu_q(a1[nt].w + b1v.w);
                const int ad = row*256 + ((w*32 + h4*8) ^ ((row&7)<<4));
                *(uint2*)(Hc + ad) = make_uint2(pack2(g0,g1), pack2(g2,g3));
            }
        }
        __syncthreads();
        #pragma unroll
        for (int ml=0; ml<2; ++ml){
            const int mtc = w*2 + ml;
            #pragma unroll
            for (int kk2=0; kk2<4; ++kk2){
                const short8 av = P2v[(mtc*32 + (ch*4 + kk2))*64 + lane];
                #pragma unroll
                for (int nt=0; nt<4; ++nt){
                    const int row = nt*16 + mcol;
                    const int ad = row*256 + ((kk2*64 + h4*16) ^ ((row&7)<<4));
                    const short8 bv = *(const short8*)(Hc + ad);
                    acc2[ml][nt] = __builtin_amdgcn_mfma_f32_16x16x32_bf16(av, bv, acc2[ml][nt], 0,0,0);
                }
            }
        }
        __syncthreads();
    }

    #pragma unroll
    for (int ml=0; ml<2; ++ml){
        const int c0 = (w*2+ml)*16 + h4*4;
        const float4 gm = *(const float4*)(cn_gamma + c0);
        const float4 b2 = *(const float4*)(pw2_b + c0);
        #pragma unroll
        for (int nt=0; nt<4; ++nt){
            const int row = nt*16 + mcol;
            const int ad = row*512 + ((2*c0) ^ ((row&7)<<4));
            const float f0 = gm.x*(acc2[ml][nt].x + b2.x);
            const float f1 = gm.y*(acc2[ml][nt].y + b2.y);
            const float f2 = gm.z*(acc2[ml][nt].z + b2.z);
            const float f3 = gm.w*(acc2[ml][nt].w + b2.w);
            *(uint2*)(Xb + ad) = make_uint2(pack2(f0,f1), pack2(f2,f3));
        }
    }
    __syncthreads();
    #pragma unroll
    for (int p=0;p<25;p++){
        const int row = sP*32 + p;
        unsigned short* ptr = (unsigned short*)(Xb + row*512 + ((2*cP) ^ ((row&7)<<4)));
        const float r = (p&1) ? bf_hi(wvp[p>>1]) : bf_lo(wvp[p>>1]);
        *ptr = f2bf(bfu(*ptr) + r);
    }
    __syncthreads();

    {
        f32x4 a3[4];
        #pragma unroll
        for (int nt=0;nt<4;nt++) a3[nt]=0.f;
        #pragma unroll
        for (int kk=0; kk<8; ++kk){
            const short8 av = Pbv[((w<<3)+kk)*64 + lane];
            #pragma unroll
            for (int nt=0; nt<4; ++nt){
                const int row = nt*16 + mcol;
                const int ad = row*512 + ((kk*64 + h4*16) ^ ((row&7)<<4));
                const short8 bv = *(const short8*)(Xb + ad);
                a3[nt] = __builtin_amdgcn_mfma_f32_16x16x32_bf16(av, bv, a3[nt], 0,0,0);
            }
        }
        const float4 bb = *(const float4*)(bn1x1_b + w*16 + h4*4);
        float e5[5];
        #pragma unroll
        for (int a=0;a<5;a++){
            const float ta = -1.f + 0.5f*a;
            e5[a] = expf(-3.125f*ta*ta);
        }
        const float Sv = e5[0]+e5[1]+e5[2]+e5[3]+e5[4];
        const float invS = 1.0f/(Sv*Sv);
        float sA[2][4];
        #pragma unroll
        for (int s=0;s<2;s++)
            #pragma unroll
            for (int j=0;j<4;j++) sA[s][j]=0.f;
        #pragma unroll
        for (int nt=0; nt<4; ++nt){
            const int row = nt*16 + mcol;
            const int s = row>>5, p = row&31;
            if (p < 25){
                const int pa = p/5, pb = p - pa*5;
                const float g = e5[pa]*e5[pb];
                sA[s][0] += g*gelu_q(a3[nt].x + bb.x);
                sA[s][1] += g*gelu_q(a3[nt].y + bb.y);
                sA[s][2] += g*gelu_q(a3[nt].z + bb.z);
                sA[s][3] += g*gelu_q(a3[nt].w + bb.w);
            }
        }
        #pragma unroll
        for (int off=1; off<16; off<<=1){
            #pragma unroll
            for (int s=0;s<2;s++)
                #pragma unroll
                for (int j=0;j<4;j++) sA[s][j] += __shfl_xor(sA[s][j], off);
        }
        if (mcol == 0){
            const int o = w*16 + h4*4;
            #pragma unroll
            for (int s=0;s<2;s++){
                float* vo = vec_out + (n0+s)*192 + o;
                vo[0]=sA[s][0]*invS; vo[1]=sA[s][1]*invS;
                vo[2]=sA[s][2]*invS; vo[3]=sA[s][3]*invS;
            }
        }
    }
}

__global__ __launch_bounds__(512,4) void bn_branch_mfma(
    const float* __restrict__ bottleneck, const float* __restrict__ pos,
    const float* __restrict__ dw_w, const float* __restrict__ dw_b,
    const float* __restrict__ ln_g, const float* __restrict__ ln_b,
    const float* __restrict__ pw1_b, const float* __restrict__ pw2_b,
    const float* __restrict__ cn_gamma, const float* __restrict__ bn1x1_b,
    const short8* __restrict__ P1v, const short8* __restrict__ P2v,
    const short8* __restrict__ Pbv,
    float* __restrict__ vec_out)
{
    __shared__ __align__(16) unsigned char U[52800];
    bn_body<false>(U, blockIdx.x*2, threadIdx.x, bottleneck, nullptr, pos, dw_w, dw_b, ln_g, ln_b,
                   pw1_b, pw2_b, cn_gamma, bn1x1_b, P1v, P2v, Pbv, vec_out);
}

__global__ __launch_bounds__(512,4) void bn_branch_mfma_tr(
    const unsigned short* __restrict__ bnT, const float* __restrict__ pos,
    const float* __restrict__ dw_w, const float* __restrict__ dw_b,
    const float* __restrict__ ln_g, const float* __restrict__ ln_b,
    const float* __restrict__ pw1_b, const float* __restrict__ pw2_b,
    const float* __restrict__ cn_gamma, const float* __restrict__ bn1x1_b,
    const short8* __restrict__ P1v, const short8* __restrict__ P2v,
    const short8* __restrict__ Pbv,
    float* __restrict__ vec_out)
{
    __shared__ __align__(16) unsigned char U[52800];
    bn_body<true>(U, blockIdx.x*2, threadIdx.x, nullptr, bnT, pos, dw_w, dw_b, ln_g, ln_b,
                  pw1_b, pw2_b, cn_gamma, bn1x1_b, P1v, P2v, Pbv, vec_out);
}

// ---- bottleneck transpose: [256][128][128] f32 -> [128][128][256] bf16 ----
__global__ __launch_bounds__(256) void transpose_bn_kernel(
    const float* __restrict__ bn, unsigned short* __restrict__ bnT)
{
    __shared__ unsigned short T[256*66];   // [c][x], pad 66
    const int b = blockIdx.x;              // 128 y x 2 xg
    const int y = b >> 1, x0 = (b & 1) << 6;
    const int t = threadIdx.x, lane = t & 63, w = t >> 6;
    for (int i = 0; i < 64; ++i){
        const int c = w*64 + i;
        T[c*66 + lane] = f2bf(bn[c*16384 + y*128 + x0 + lane]);
    }
    __syncthreads();
    const int x = t >> 2, q = (t & 3) * 64;
    #pragma unroll
    for (int h = 0; h < 8; ++h){
        const int cg = q + h*8;
        unsigned int v[4];
        #pragma unroll
        for (int j = 0; j < 4; ++j){
            const unsigned int a = T[(cg + 2*j    )*66 + x];
            const unsigned int bs = T[(cg + 2*j + 1)*66 + x];
            v[j] = a | (bs << 16);
        }
        *(uint4*)(bnT + ((size_t)(y*128) + x0 + x)*256 + cg) = make_uint4(v[0],v[1],v[2],v[3]);
    }
}

// ---- bn weight prepack (proven) ----
__global__ __launch_bounds__(256) void prepack_bn_kernel(
    const float* __restrict__ W1, const float* __restrict__ W2, const float* __restrict__ Wb,
    unsigned short* __restrict__ P1, unsigned short* __restrict__ P2, unsigned short* __restrict__ Pb)
{
    const int tid = blockIdx.x*256 + threadIdx.x;
    const float* src; unsigned short* dst; int row, col, stride, idx;
    if (tid < 32768){
        idx = tid;
        const int frag = idx>>6, l = idx&63;
        row = (frag>>3)*16 + (l&15); col = (frag&7)*32 + (l>>4)*8; stride = 256;
        src = W1; dst = P1;
    } else if (tid < 65536){
        idx = tid - 32768;
        const int frag = idx>>6, l = idx&63;
        row = (frag>>5)*16 + (l&15); col = (frag&31)*32 + (l>>4)*8; stride = 1024;
        src = W2; dst = P2;
    } else if (tid < 69632){
        idx = tid - 65536;
        const int frag = idx>>6, l = idx&63;
        row = (frag>>3)*16 + (l&15); col = (frag&7)*32 + (l>>4)*8; stride = 256;
        src = Wb; dst = Pb;
    } else return;
    const float* s = src + row*stride + col;
    unsigned int v[4];
    #pragma unroll
    for (int j=0;j<4;j++) v[j] = pack2(s[2*j], s[2*j+1]);
    *(uint4*)(dst + (size_t)idx*8) = make_uint4(v[0],v[1],v[2],v[3]);
}

// ---------------- Stem weight prepack (proven r9) ----------------
__global__ __launch_bounds__(256) void prepack_kernel(
    const float* __restrict__ W1, const float* __restrict__ W2,
    unsigned short* __restrict__ Ap)
{
    const int tid = blockIdx.x*256 + threadIdx.x;
    if (tid >= 9216) return;
    const int conv = tid / 4608;
    const int r = tid - conv*4608;
    const int frag = r >> 6, l = r & 63;
    const int k  = frag >> 3;
    const int kt = (frag >> 1) & 3;
    const int wo = frag & 1;
    const float* W = conv ? W2 : W1;
    const int o  = wo*32 + (l & 31);
    const int c0 = kt*16 + (l >> 5)*8;
    unsigned int v[4];
    #pragma unroll
    for (int jj=0; jj<4; jj++){
        const float f0 = W[o*576 + (c0+2*jj  )*9 + k];
        const float f1 = W[o*576 + (c0+2*jj+1)*9 + k];
        v[jj] = pack2(f0, f1);
    }
    *(uint4*)(Ap + (size_t)tid*8) = make_uint4(v[0], v[1], v[2], v[3]);
}

// ---------------- vis transpose (proven r13) ----------------
__global__ __launch_bounds__(256) void transpose_vis_kernel(
    const float* __restrict__ vis, unsigned short* __restrict__ visT)
{
    __shared__ unsigned short T[64*66];
    const int b = blockIdx.x;
    const int y = b >> 4, x0 = (b & 15) << 6;
    const int t = threadIdx.x, lane = t & 63, w = t >> 6;
    #pragma unroll
    for (int i = 0; i < 16; ++i){
        const int c = w*16 + i;
        T[c*66 + lane] = f2bf(vis[c*1048576 + y*1024 + x0 + lane]);
    }
    __syncthreads();
    const int x = t >> 2, cg0 = (t & 3) * 16;
    #pragma unroll
    for (int h = 0; h < 2; ++h){
        const int cg = cg0 + h*8;
        unsigned int v[4];
        #pragma unroll
        for (int j = 0; j < 4; ++j){
            const unsigned int a = T[(cg + 2*j    )*66 + x];
            const unsigned int bsh = T[(cg + 2*j + 1)*66 + x];
            v[j] = a | (bsh << 16);
        }
        *(uint4*)(visT + ((size_t)(y*1024) + x0 + x)*64 + cg) = make_uint4(v[0],v[1],v[2],v[3]);
    }
}

// ================= Stem body (proven r9-r13) =================
#define STEM_CONV32(SRC, AP)                                                        \
    _Pragma("unroll")                                                               \
    for (int k=0;k<9;k++){                                                          \
        int tj[3];                                                                  \
        _Pragma("unroll")                                                           \
        for (int j=0;j<3;j++)                                                       \
            tj[j] = (int)sTab[m*90 + (j<cnt ? st+j : st)*9 + k];                    \
        _Pragma("unroll")                                                           \
        for (int kt=0;kt<4;kt++){                                                   \
            const short8 av = (AP)[(k*8 + kt*2 + wo)*64 + lane];                    \
            const int cb = kt*32 + hi16;                                            \
            _Pragma("unroll")                                                       \
            for (int j=0;j<3;j++){                                                  \
                if (j < cnt){                                                       \
                    const short8 bv = *(const short8*)((SRC) + (tj[j] ^ cb));       \
                    acc[j] = __builtin_amdgcn_mfma_f32_32x32x16_bf16(av, bv, acc[j], 0,0,0); \
                }                                                                   \
            }                                                                       \
        }                                                                           \
    }

template<bool TR>
__device__ __forceinline__ void stem_body(
    unsigned char* __restrict__ U, int n, int t,
    const float* __restrict__ vis, const unsigned short* __restrict__ visT,
    const float* __restrict__ pos,
    const short8* __restrict__ Ap1,
    const float* __restrict__ st1_b, const float* __restrict__ st2_b,
    float* __restrict__ vec_out)
{
    unsigned char* sXt = U;
    unsigned short* sTab = (unsigned short*)(U + 37120);
    float (*redS)[4] = (float(*)[4])(U + 42880);

    const int lane = t & 63;
    const int m = lane & 31;
    const int hi = lane >> 5;
    const int hi16 = hi*16;
    const int w = t >> 6;
    const int wo = w & 1;
    const int nh = w >> 1;
    const int st  = nh*3 - (nh==3 ? 1 : 0);
    const int cnt = (nh < 2) ? 3 : 2;

    const float fpx0 = pos[2*n], fpy0 = pos[2*n+1];
    const float fpx = floorf(fpx0), fpy = floorf(fpy0);
    const int ix0 = (int)fpx - 8, iy0 = (int)fpy - 8;
    const float fx = fpx0-fpx, fy = fpy0-fpy;
    const float w00=(1.f-fy)*(1.f-fx), w01=(1.f-fy)*fx, w10=fy*(1.f-fx), w11=fy*fx;

    if (t < 32) *(unsigned int*)(sXt + 289*128 + t*4) = 0u;

    for (int idx = t; idx < 32*90; idx += 512){
        const int mm = idx/90, rem = idx - mm*90;
        const int nt = rem/9, k = rem - nt*9;
        const int p = nt*32 + mm;
        int pp = 289;
        if (p < 289){
            const int py = (p*241)>>12, px = p - py*17;
            const int y = py + k/3 - 1, x = px + (k - (k/3)*3) - 1;
            if (((unsigned)y < 17u) && ((unsigned)x < 17u)) pp = y*17 + x;
        }
        sTab[idx] = (unsigned short)(pp*128 + ((pp&7)<<4));
    }

    if (TR){
        for (int idx = t; idx < 289*8; idx += 512){
            const int p = idx >> 3, cg = (idx & 7) * 8;
            const int py = (p*241)>>12, px = p - py*17;
            const unsigned short* q = visT + (size_t)((iy0+py)*1024 + (ix0+px))*64 + cg;
            const uint4 q00 = *(const uint4*)(q);
            const uint4 q01 = *(const uint4*)(q + 64);
            const uint4 q10 = *(const uint4*)(q + 65536);
            const uint4 q11 = *(const uint4*)(q + 65536 + 64);
            unsigned int o[4];
            #pragma unroll
            for (int j=0;j<4;j++){
                const unsigned int u00=((const unsigned int*)&q00)[j];
                const unsigned int u01=((const unsigned int*)&q01)[j];
                const unsigned int u10=((const unsigned int*)&q10)[j];
                const unsigned int u11=((const unsigned int*)&q11)[j];
                const float lo = bf_lo(u00)*w00 + bf_lo(u01)*w01 + bf_lo(u10)*w10 + bf_lo(u11)*w11;
                const float hv = bf_hi(u00)*w00 + bf_hi(u01)*w01 + bf_hi(u10)*w10 + bf_hi(u11)*w11;
                o[j] = pack2(lo, hv);
            }
            *(uint4*)(sXt + p*128 + ((2*cg) ^ ((p&7)<<4))) = make_uint4(o[0],o[1],o[2],o[3]);
        }
    } else {
        for (int task = t; task < 64*17; task += 512){
            const int c  = task & 63;
            const int py = task >> 6;
            const float* r0 = vis + c*1048576 + (iy0+py)*1024 + ix0;
            float a[18], b[18];
            #pragma unroll
            for (int kk=0; kk<18; kk++){ a[kk]=r0[kk]; b[kk]=r0[1024+kk]; }
            #pragma unroll
            for (int px=0; px<17; px++){
                const float v = w00*a[px] + w01*a[px+1] + w10*b[px] + w11*b[px+1];
                const int p = py*17 + px;
                *(unsigned short*)(sXt + p*128 + ((2*c) ^ ((p&7)<<4))) = f2bf(v);
            }
        }
    }
    __syncthreads();

    f32x16 acc[3];
    #pragma unroll
    for (int j=0;j<3;j++) acc[j] = 0.f;
    STEM_CONV32(sXt, Ap1)

    uint2 pk[3][4];
    {
        float4 b4[4];
        #pragma unroll
        for (int rg=0;rg<4;rg++) b4[rg] = *(const float4*)(st1_b + wo*32 + 8*rg + 4*hi);
        #pragma unroll
        for (int j=0;j<3;j++){
            if (j < cnt){
                #pragma unroll
                for (int rg=0;rg<4;rg++){
                    const float v0 = gelu_q(acc[j][4*rg+0] + b4[rg].x);
                    const float v1 = gelu_q(acc[j][4*rg+1] + b4[rg].y);
                    const float v2 = gelu_q(acc[j][4*rg+2] + b4[rg].z);
                    const float v3 = gelu_q(acc[j][4*rg+3] + b4[rg].w);
                    pk[j][rg] = make_uint2(pack2(v0,v1), pack2(v2,v3));
                }
            }
        }
    }
    __syncthreads();

    #pragma unroll
    for (int j=0;j<3;j++){
        if (j < cnt){
            const int p = (st+j)*32 + m;
            if (p < 289){
                const int swz = (p&7)<<4;
                #pragma unroll
                for (int rg=0;rg<4;rg++){
                    const int ch0 = wo*32 + 8*rg + 4*hi;
                    *(uint2*)(sXt + p*128 + ((2*ch0) ^ swz)) = pk[j][rg];
                }
            }
        }
    }
    __syncthreads();

    const short8* Ap2 = Ap1 + 4608;
    #pragma unroll
    for (int j=0;j<3;j++) acc[j] = 0.f;
    STEM_CONV32(sXt, Ap2)

    {
        float4 b4[4];
        #pragma unroll
        for (int rg=0;rg<4;rg++) b4[rg] = *(const float4*)(st2_b + wo*32 + 8*rg + 4*hi);
        float s[16];
        #pragma unroll
        for (int r=0;r<16;r++) s[r]=0.f;
        #pragma unroll
        for (int j=0;j<3;j++){
            if (j < cnt){
                const int p = (st+j)*32 + m;
                if (p < 289){
                    const int py = (p*241)>>12;
                    const int px = p - py*17;
                    const float ty = -1.f + 0.125f*py;
                    const float tx = -1.f + 0.125f*px;
                    const float g = expf(-3.125f*(ty*ty + tx*tx));
                    #pragma unroll
                    for (int rg=0;rg<4;rg++){
                        s[4*rg+0] += g*gelu_q(acc[j][4*rg+0] + b4[rg].x);
                        s[4*rg+1] += g*gelu_q(acc[j][4*rg+1] + b4[rg].y);
                        s[4*rg+2] += g*gelu_q(acc[j][4*rg+2] + b4[rg].z);
                        s[4*rg+3] += g*gelu_q(acc[j][4*rg+3] + b4[rg].w);
                    }
                }
            }
        }
        #pragma unroll
        for (int off=1; off<32; off<<=1){
            #pragma unroll
            for (int r=0;r<16;r++) s[r] += __shfl_xor(s[r], off);
        }
        if (m == 0){
            #pragma unroll
            for (int rg=0;rg<4;rg++)
                #pragma unroll
                for (int e=0;e<4;e++)
                    redS[wo*32 + 8*rg + 4*hi + e][nh] = s[4*rg+e];
        }
    }
    __syncthreads();
    if (t < 64){
        float Sv = 0.f;
        #pragma unroll
        for (int j=0;j<17;j++){
            const float tj = -1.f + 0.125f*j;
            Sv += expf(-3.125f*tj*tj);
        }
        vec_out[n*192+128+t] = (redS[t][0] + redS[t][1] + redS[t][2] + redS[t][3]) / (Sv*Sv);
    }
}

__global__ __launch_bounds__(512,4) void stem_kernel_tr(
    const unsigned short* __restrict__ visT, const float* __restrict__ pos,
    const short8* __restrict__ Ap1,
    const float* __restrict__ st1_b, const float* __restrict__ st2_b,
    float* __restrict__ vec_out)
{
    __shared__ __align__(16) unsigned char U[43904];
    stem_body<true>(U, blockIdx.x, threadIdx.x, nullptr, visT, pos, Ap1, st1_b, st2_b, vec_out);
}

__global__ __launch_bounds__(512,4) void stem_branch_kernel(
    const float* __restrict__ vis, const float* __restrict__ pos,
    const short8* __restrict__ Ap1,
    const float* __restrict__ st1_b, const float* __restrict__ st2_b,
    float* __restrict__ vec_out)
{
    __shared__ __align__(16) unsigned char U[43904];
    stem_body<false>(U, blockIdx.x, threadIdx.x, vis, nullptr, pos, Ap1, st1_b, st2_b, vec_out);
}

// ---------------- Head: 16 samples/block (proven) ----------------
__global__ __launch_bounds__(128) void head16_kernel(
    const float* __restrict__ vec, const float* __restrict__ p2s,
    const float* __restrict__ h1_w, const float* __restrict__ h1_b,
    const float* __restrict__ h2_w, const float* __restrict__ h2_b,
    const float* __restrict__ h3_w, const float* __restrict__ h3_b,
    float* __restrict__ out, int N)
{
    __shared__ float v[16][192];
    __shared__ float x1s[16][132];
    __shared__ float x2s[16][132];
    __shared__ float o3s[16][4];
    const int n0 = blockIdx.x*16, t = threadIdx.x;

    for (int idx=t; idx<16*192; idx+=128){
        const int s = idx/192, k = idx - s*192;
        v[s][k] = vec[n0*192 + idx];
    }
    __syncthreads();
    {
        const int o = t;
        float acc[16];
        const float b = h1_b[o];
        #pragma unroll
        for (int s=0;s<16;s++) acc[s]=b;
        const float4* wr = (const float4*)(h1_w + o*192);
        for (int k4=0;k4<48;k4++){
            const float4 wv4 = wr[k4];
            #pragma unroll
            for (int s=0;s<16;s++){
                const float4 vv = *(const float4*)&v[s][k4*4];
                acc[s] += wv4.x*vv.x + wv4.y*vv.y + wv4.z*vv.z + wv4.w*vv.w;
            }
        }
        #pragma unroll
        for (int s=0;s<16;s++) x1s[s][o] = gelu_f(acc[s]);
    }
    __syncthreads();
    {
        const int o = t;
        float acc[16];
        const float b = h2_b[o];
        #pragma unroll
        for (int s=0;s<16;s++) acc[s]=b;
        const float4* wr = (const float4*)(h2_w + o*128);
        for (int k4=0;k4<32;k4++){
            const float4 wv4 = wr[k4];
            #pragma unroll
            for (int s=0;s<16;s++){
                const float4 vv = *(const float4*)&x1s[s][k4*4];
                acc[s] += wv4.x*vv.x + wv4.y*vv.y + wv4.z*vv.z + wv4.w*vv.w;
            }
        }
        #pragma unroll
        for (int s=0;s<16;s++) x2s[s][o] = gelu_f(acc[s]);
    }
    __syncthreads();
    if (t < 48){
        const int j = t>>4, s = t&15;
        float a = h3_b[j];
        const float* wr = h3_w + j*128;
        for (int k=0;k<128;k++) a += x2s[s][k]*wr[k];
        o3s[s][j] = a;
    }
    __syncthreads();
    if (t < 16){
        const int s = t, n = n0 + s;
        const float dx = o3s[s][0], dy = o3s[s][1];
        float ls = o3s[s][2];
        ls = ls < -6.f ? -6.f : (ls > 3.f ? 3.f : ls);
        const float s0 = p2s[n*4+0]*dx + p2s[n*4+1]*dy;
        const float s1 = p2s[n*4+2]*dx + p2s[n*4+3]*dy;
        const float conf = 1.0f/fmaxf(expf(ls), 1e-4f);
        out[2*n]   = s0;
        out[2*n+1] = s1;
        out[2*N+n] = dx;
        out[3*N+n] = dy;
        out[4*N+n] = ls;
        out[5*N+n] = conf;
    }
}

extern "C" void kernel_launch(void* const* d_in, const int* in_sizes, int n_in,
                              void* d_out, int out_size, void* d_ws, size_t ws_size,
                              hipStream_t stream)
{
    (void)n_in; (void)out_size;
    const float* bottleneck = (const float*)d_in[0];
    const float* vis        = (const float*)d_in[1];
    const float* pos        = (const float*)d_in[2];
    const float* p2s        = (const float*)d_in[3];
    const float* dw_w  = (const float*)d_in[8];
    const float* dw_b  = (const float*)d_in[9];
    const float* ln_g  = (const float*)d_in[10];
    const float* ln_b  = (const float*)d_in[11];
    const float* pw1_w = (const float*)d_in[12];
    const float* pw1_b = (const float*)d_in[13];
    const float* pw2_w = (const float*)d_in[14];
    const float* pw2_b = (const float*)d_in[15];
    const float* gam   = (const float*)d_in[16];
    const float* b1w   = (const float*)d_in[17];
    const float* b1b   = (const float*)d_in[18];
    const float* s1w   = (const float*)d_in[19];
    const float* s1b   = (const float*)d_in[20];
    const float* s2w   = (const float*)d_in[21];
    const float* s2b   = (const float*)d_in[22];
    const float* h1w   = (const float*)d_in[23];
    const float* h1b   = (const float*)d_in[24];
    const float* h2w   = (const float*)d_in[25];
    const float* h2b   = (const float*)d_in[26];
    const float* h3w   = (const float*)d_in[27];
    const float* h3b   = (const float*)d_in[28];

    const int N = in_sizes[2]/2;            // 4096
    char* ws = (char*)d_ws;
    float* vec = (float*)ws;                                  // 3,145,728
    unsigned short* Apack = (unsigned short*)(ws + 3145728);  //   147,456
    unsigned short* P1    = (unsigned short*)(ws + 3293184);  //   524,288
    unsigned short* P2    = (unsigned short*)(ws + 3817472);  //   524,288
    unsigned short* Pb    = (unsigned short*)(ws + 4341760);  //    65,536
    unsigned short* visT  = (unsigned short*)(ws + 4407296);  // 134,217,728
    unsigned short* bnT   = (unsigned short*)(ws + 4407296 + 134217728ull); // 8,388,608
    const size_t need_mfma = 4407296u;
    const size_t need_tr   = 4407296u + 134217728ull;
    const size_t need_full = need_tr + 8388608ull;
    const size_t vec_bytes = (size_t)N*192*sizeof(float);

    hipMemsetAsync(d_ws, 0, vec_bytes, stream);
    prepack_kernel<<<36, 256, 0, stream>>>(s1w, s2w, Apack);

    if (ws_size >= need_full){
        prepack_bn_kernel<<<272, 256, 0, stream>>>(pw1_w, pw2_w, b1w, P1, P2, Pb);
        transpose_bn_kernel<<<256, 256, 0, stream>>>(bottleneck, bnT);
        transpose_vis_kernel<<<16384, 256, 0, stream>>>(vis, visT);
        stem_kernel_tr<<<N, 512, 0, stream>>>(visT, pos, (const short8*)Apack, s1b, s2b, vec);
        bn_branch_mfma_tr<<<N/2, 512, 0, stream>>>(bnT, pos, dw_w, dw_b, ln_g, ln_b,
                                                   pw1_b, pw2_b, gam, b1b,
                                                   (const short8*)P1, (const short8*)P2, (const short8*)Pb,
                                                   vec);
    } else if (ws_size >= need_tr){
        prepack_bn_kernel<<<272, 256, 0, stream>>>(pw1_w, pw2_w, b1w, P1, P2, Pb);
        transpose_vis_kernel<<<16384, 256, 0, stream>>>(vis, visT);
        stem_kernel_tr<<<N, 512, 0, stream>>>(visT, pos, (const short8*)Apack, s1b, s2b, vec);
        bn_branch_mfma<<<N/2, 512, 0, stream>>>(bottleneck, pos, dw_w, dw_b, ln_g, ln_b,
                                                pw1_b, pw2_b, gam, b1b,
                                                (const short8*)P1, (const short8*)P2, (const short8*)Pb,
                                                vec);
    } else {
        prepack_bn_kernel<<<272, 256, 0, stream>>>(pw1_w, pw2_w, b1w, P1, P2, Pb);
        bn_branch_mfma<<<N/2, 512, 0, stream>>>(bottleneck, pos, dw_w, dw_b, ln_g, ln_b,
                                                pw1_b, pw2_b, gam, b1b,
                                                (const short8*)P1, (const short8*)P2, (const short8*)Pb,
                                                vec);
        stem_branch_kernel<<<N, 512, 0, stream>>>(vis, pos, (const short8*)Apack, s1b, s2b, vec);
    }
    head16_kernel<<<N/16, 128, 0, stream>>>(vec, p2s, h1w, h1b, h2w, h2b, h3w, h3b,
                                            (float*)d_out, N);
}

// Round 15
// 738.861 us; speedup vs baseline: 1.1765x; 1.0005x over previous
//
#include <hip/hip_runtime.h>
#include <hip/hip_bf16.h>

#define XSTR 28   // legacy BN VALU kernel stride

typedef short short8 __attribute__((ext_vector_type(8)));
typedef float f32x4  __attribute__((ext_vector_type(4)));
typedef float f32x16 __attribute__((ext_vector_type(16)));

__device__ __forceinline__ float gelu_f(float x){
    return 0.5f*x*(1.0f + erff(x*0.70710678118654752f));
}
__device__ __forceinline__ float gelu_q(float x){
    const float z = 1.5957691216057308f*x*(1.0f + 0.044715f*x*x);
    return x / (1.0f + __expf(-z));
}
__device__ __forceinline__ unsigned short f2bf(float f){
    unsigned int u = __float_as_uint(f);
    u += 0x7fffu + ((u>>16)&1u);
    return (unsigned short)(u>>16);
}
__device__ __forceinline__ unsigned int pack2(float a, float b){
    return (unsigned int)f2bf(a) | ((unsigned int)f2bf(b)<<16);
}
__device__ __forceinline__ float bf_lo(unsigned int u){ return __uint_as_float(u<<16); }
__device__ __forceinline__ float bf_hi(unsigned int u){ return __uint_as_float(u & 0xffff0000u); }
__device__ __forceinline__ float bfu(unsigned short v){ return __uint_as_float(((unsigned int)v)<<16); }

__device__ __forceinline__ void fma_row25(const float* __restrict__ row, float w, float* __restrict__ acc){
    const float4* r4 = (const float4*)row;
    float4 a0=r4[0], a1=r4[1], a2=r4[2], a3=r4[3], a4=r4[4], a5=r4[5];
    float a6 = row[24];
    acc[0]+=a0.x*w;  acc[1]+=a0.y*w;  acc[2]+=a0.z*w;  acc[3]+=a0.w*w;
    acc[4]+=a1.x*w;  acc[5]+=a1.y*w;  acc[6]+=a1.z*w;  acc[7]+=a1.w*w;
    acc[8]+=a2.x*w;  acc[9]+=a2.y*w;  acc[10]+=a2.z*w; acc[11]+=a2.w*w;
    acc[12]+=a3.x*w; acc[13]+=a3.y*w; acc[14]+=a3.z*w; acc[15]+=a3.w*w;
    acc[16]+=a4.x*w; acc[17]+=a4.y*w; acc[18]+=a4.z*w; acc[19]+=a4.w*w;
    acc[20]+=a5.x*w; acc[21]+=a5.y*w; acc[22]+=a5.z*w; acc[23]+=a5.w*w;
    acc[24]+=a6*w;
}

// ================= BN body: r14 pipeline + double-buffered Hc (1 barrier/chunk) =================
// U layout: Xb 32768 | Hc0 16384 | Hc1 16384 | redA 1600 | redB 1600 | muS 224 | rsS 224 = 69184
template<bool BTR>
__device__ __forceinline__ void bn_body(
    unsigned char* __restrict__ U, int n0, int t,
    const float* __restrict__ bottleneck, const unsigned short* __restrict__ bnT,
    const float* __restrict__ pos,
    const float* __restrict__ dw_w, const float* __restrict__ dw_b,
    const float* __restrict__ ln_g, const float* __restrict__ ln_b,
    const float* __restrict__ pw1_b, const float* __restrict__ pw2_b,
    const float* __restrict__ cn_gamma, const float* __restrict__ bn1x1_b,
    const short8* __restrict__ P1v, const short8* __restrict__ P2v,
    const short8* __restrict__ Pbv,
    float* __restrict__ vec_out)
{
    unsigned char* Xb  = U;
    unsigned char* Hc0 = U + 32768;
    unsigned char* Hc1 = U + 49152;
    float* redA = (float*)(U + 65536);
    float* redB = (float*)(U + 67136);
    float* muS  = (float*)(U + 68736);
    float* rsS  = (float*)(U + 68960);

    const int lane = t & 63, w = t >> 6;
    const int mcol = lane & 15, h4 = lane >> 4;
    const int sP = t >> 8, cP = t & 255;

    unsigned int wvp[13];

    if (BTR){
        // ---- Phase A: coalesced blend from channel-last bnT into Xb (swizzled) ----
        int ix0A[2], iy0A[2];
        float wbl[2][4];
        #pragma unroll
        for (int s=0;s<2;s++){
            const int n = n0 + s;
            const float px = pos[2*n]*0.125f, py = pos[2*n+1]*0.125f;
            const float fpx = floorf(px), fpy = floorf(py);
            ix0A[s] = (int)fpx - 2; iy0A[s] = (int)fpy - 2;
            const float fx = px - fpx, fy = py - fpy;
            wbl[s][0]=(1.f-fy)*(1.f-fx); wbl[s][1]=(1.f-fy)*fx;
            wbl[s][2]=fy*(1.f-fx);       wbl[s][3]=fy*fx;
        }
        for (int idx = t; idx < 1600; idx += 512){
            const int s = idx/800, rem = idx - s*800;
            const int p = rem >> 5, cg = rem & 31;
            const int a = p/5, bq = p - a*5;
            const int y0 = iy0A[s]+a, x0 = ix0A[s]+bq;
            uint4 q[4];
            #pragma unroll
            for (int e=0;e<4;e++){
                const int yy = y0 + (e>>1), xx = x0 + (e&1);
                const bool ok = ((unsigned)yy < 128u) && ((unsigned)xx < 128u);
                q[e] = ok ? *(const uint4*)(bnT + ((size_t)(yy*128+xx))*256 + cg*8)
                          : make_uint4(0u,0u,0u,0u);
            }
            const float w0=wbl[s][0], w1=wbl[s][1], w2=wbl[s][2], w3=wbl[s][3];
            unsigned int o[4];
            #pragma unroll
            for (int j=0;j<4;j++){
                const unsigned int u0=((const unsigned int*)&q[0])[j];
                const unsigned int u1=((const unsigned int*)&q[1])[j];
                const unsigned int u2=((const unsigned int*)&q[2])[j];
                const unsigned int u3=((const unsigned int*)&q[3])[j];
                const float lo = bf_lo(u0)*w0 + bf_lo(u1)*w1 + bf_lo(u2)*w2 + bf_lo(u3)*w3;
                const float hv = bf_hi(u0)*w0 + bf_hi(u1)*w1 + bf_hi(u2)*w2 + bf_hi(u3)*w3;
                o[j] = pack2(lo, hv);
            }
            const int row = s*32 + p;
            *(uint4*)(Xb + row*512 + ((cg*16) ^ ((row&7)<<4))) = make_uint4(o[0],o[1],o[2],o[3]);
        }
        __syncthreads();
        // ---- Phase B: thread=(s,c) reads its window, packs residual, depthwise ----
        {
            float wv[25];
            #pragma unroll
            for (int p=0;p<25;p++){
                const int row = sP*32 + p;
                wv[p] = bfu(*(const unsigned short*)(Xb + row*512 + ((2*cP) ^ ((row&7)<<4))));
            }
            #pragma unroll
            for (int i=0;i<12;i++) wvp[i] = pack2(wv[2*i], wv[2*i+1]);
            wvp[12] = pack2(wv[24], 0.f);
            float xdw[25];
            {
                float wcr[49];
                const float* wc = dw_w + cP*49;
                #pragma unroll
                for (int k=0;k<49;k++) wcr[k]=wc[k];
                const float bb = dw_b[cP];
                #pragma unroll
                for (int i=0;i<5;i++){
                    #pragma unroll
                    for (int j=0;j<5;j++){
                        float a = bb;
                        #pragma unroll
                        for (int u=0;u<7;u++){
                            const int y = i+u-3;
                            if (y<0||y>4) continue;
                            #pragma unroll
                            for (int v=0;v<7;v++){
                                const int x = j+v-3;
                                if (x<0||x>4) continue;
                                a += wv[y*5+x]*wcr[u*7+v];
                            }
                        }
                        xdw[i*5+j] = a;
                    }
                }
            }
            #pragma unroll
            for (int p=0;p<25;p++){
                const int row = sP*32 + p;
                *(unsigned short*)(Xb + row*512 + ((2*cP) ^ ((row&7)<<4))) = f2bf(xdw[p]);
            }
        }
    } else {
        const int n = n0 + sP;
        const float px = pos[2*n]*0.125f, py = pos[2*n+1]*0.125f;
        const float fpx = floorf(px), fpy = floorf(py);
        const int ix0 = (int)fpx - 2, iy0 = (int)fpy - 2;
        const float fx = px - fpx, fy = py - fpy;
        const float w00=(1.f-fy)*(1.f-fx), w01=(1.f-fy)*fx, w10=fy*(1.f-fx), w11=fy*fx;
        float wv[25];
        {
            const float* fm = bottleneck + cP*16384;
            float P[6][6];
            #pragma unroll
            for (int r=0;r<6;r++){
                const int y = iy0+r;
                const bool yok = (y>=0)&&(y<128);
                const int yc = y<0?0:(y>127?127:y);
                #pragma unroll
                for (int s=0;s<6;s++){
                    const int x = ix0+s;
                    const bool ok = yok && (x>=0) && (x<128);
                    const int xc = x<0?0:(x>127?127:x);
                    P[r][s] = ok ? fm[yc*128+xc] : 0.f;
                }
            }
            #pragma unroll
            for (int a=0;a<5;a++)
            #pragma unroll
            for (int b=0;b<5;b++)
                wv[a*5+b] = w00*P[a][b]+w01*P[a][b+1]+w10*P[a+1][b]+w11*P[a+1][b+1];
        }
        #pragma unroll
        for (int i=0;i<12;i++) wvp[i] = pack2(wv[2*i], wv[2*i+1]);
        wvp[12] = pack2(wv[24], 0.f);
        float xdw[25];
        {
            float wcr[49];
            const float* wc = dw_w + cP*49;
            #pragma unroll
            for (int k=0;k<49;k++) wcr[k]=wc[k];
            const float bb = dw_b[cP];
            #pragma unroll
            for (int i=0;i<5;i++){
                #pragma unroll
                for (int j=0;j<5;j++){
                    float a = bb;
                    #pragma unroll
                    for (int u=0;u<7;u++){
                        const int y = i+u-3;
                        if (y<0||y>4) continue;
                        #pragma unroll
                        for (int v=0;v<7;v++){
                            const int x = j+v-3;
                            if (x<0||x>4) continue;
                            a += wv[y*5+x]*wcr[u*7+v];
                        }
                    }
                    xdw[i*5+j] = a;
                }
            }
        }
        #pragma unroll
        for (int p=0;p<25;p++){
            const int row = sP*32 + p;
            *(unsigned short*)(Xb + row*512 + ((2*cP) ^ ((row&7)<<4))) = f2bf(xdw[p]);
        }
    }
    __syncthreads();
    if (t < 400){
        const int sp = t>>3, part = t&7;
        const int row = (sp/25)*32 + (sp - (sp/25)*25);
        float a=0.f, b=0.f;
        for (int c=part; c<256; c+=8){
            const float v = bfu(*(const unsigned short*)(Xb + row*512 + ((2*c) ^ ((row&7)<<4))));
            a += v; b += v*v;
        }
        redA[t]=a; redB[t]=b;
    }
    __syncthreads();
    if (t < 50){
        float a=0.f, b=0.f;
        #pragma unroll
        for (int s=0;s<8;s++){ a+=redA[t*8+s]; b+=redB[t*8+s]; }
        const float m = a*(1.f/256.f);
        const float var = b*(1.f/256.f) - m*m;
        muS[t]=m; rsS[t]=rsqrtf(var+1e-6f);
    }
    __syncthreads();
    {
        const float g = ln_g[cP], bb = ln_b[cP];
        #pragma unroll
        for (int p=0;p<25;p++){
            const int row = sP*32 + p;
            unsigned short* ptr = (unsigned short*)(Xb + row*512 + ((2*cP) ^ ((row&7)<<4)));
            const float xv = bfu(*ptr);
            *ptr = f2bf((xv-muS[sP*25+p])*rsS[sP*25+p]*g + bb);
        }
    }
    __syncthreads();

    // ---- chunked pw1 -> pw2 with double-buffered Hc: 1 barrier per chunk ----
    f32x4 acc2[2][4];
    #pragma unroll
    for (int ml=0;ml<2;ml++)
        #pragma unroll
        for (int nt=0;nt<4;nt++) acc2[ml][nt]=0.f;

    // prologue: pw1 chunk 0 -> Hc0
    {
        const int mt = w;
        f32x4 a1[4];
        #pragma unroll
        for (int nt=0;nt<4;nt++) a1[nt]=0.f;
        #pragma unroll
        for (int kk=0; kk<8; ++kk){
            const short8 av = P1v[((mt<<3)+kk)*64 + lane];
            #pragma unroll
            for (int nt=0; nt<4; ++nt){
                const int row = nt*16 + mcol;
                const int ad = row*512 + ((kk*64 + h4*16) ^ ((row&7)<<4));
                const short8 bv = *(const short8*)(Xb + ad);
                a1[nt] = __builtin_amdgcn_mfma_f32_16x16x32_bf16(av, bv, a1[nt], 0,0,0);
            }
        }
        const float4 b1v = *(const float4*)(pw1_b + mt*16 + h4*4);
        #pragma unroll
        for (int nt=0; nt<4; ++nt){
            const int row = nt*16 + mcol;
            const int ad = row*256 + ((w*32 + h4*8) ^ ((row&7)<<4));
            *(uint2*)(Hc0 + ad) = make_uint2(
                pack2(gelu_q(a1[nt].x + b1v.x), gelu_q(a1[nt].y + b1v.y)),
                pack2(gelu_q(a1[nt].z + b1v.z), gelu_q(a1[nt].w + b1v.w)));
        }
    }
    __syncthreads();
    for (int ch=1; ch<=8; ++ch){
        unsigned char* Hr = ((ch-1)&1) ? Hc1 : Hc0;
        if (ch < 8){
            unsigned char* Hw = (ch&1) ? Hc1 : Hc0;
            const int mt = ch*8 + w;
            f32x4 a1[4];
            #pragma unroll
            for (int nt=0;nt<4;nt++) a1[nt]=0.f;
            #pragma unroll
            for (int kk=0; kk<8; ++kk){
                const short8 av = P1v[((mt<<3)+kk)*64 + lane];
                #pragma unroll
                for (int nt=0; nt<4; ++nt){
                    const int row = nt*16 + mcol;
                    const int ad = row*512 + ((kk*64 + h4*16) ^ ((row&7)<<4));
                    const short8 bv = *(const short8*)(Xb + ad);
                    a1[nt] = __builtin_amdgcn_mfma_f32_16x16x32_bf16(av, bv, a1[nt], 0,0,0);
                }
            }
            const float4 b1v = *(const float4*)(pw1_b + mt*16 + h4*4);
            #pragma unroll
            for (int nt=0; nt<4; ++nt){
                const int row = nt*16 + mcol;
                const int ad = row*256 + ((w*32 + h4*8) ^ ((row&7)<<4));
                *(uint2*)(Hw + ad) = make_uint2(
                    pack2(gelu_q(a1[nt].x + b1v.x), gelu_q(a1[nt].y + b1v.y)),
                    pack2(gelu_q(a1[nt].z + b1v.z), gelu_q(a1[nt].w + b1v.w)));
            }
        }
        #pragma unroll
        for (int ml=0; ml<2; ++ml){
            const int mtc = w*2 + ml;
            #pragma unroll
            for (int kk2=0; kk2<4; ++kk2){
                const short8 av = P2v[(mtc*32 + ((ch-1)*4 + kk2))*64 + lane];
                #pragma unroll
                for (int nt=0; nt<4; ++nt){
                    const int row = nt*16 + mcol;
                    const int ad = row*256 + ((kk2*64 + h4*16) ^ ((row&7)<<4));
                    const short8 bv = *(const short8*)(Hr + ad);
                    acc2[ml][nt] = __builtin_amdgcn_mfma_f32_16x16x32_bf16(av, bv, acc2[ml][nt], 0,0,0);
                }
            }
        }
        if (ch < 8) __syncthreads();
    }

    // ---- pw2 epilogue: gamma*(acc+b2) -> Xb ----
    #pragma unroll
    for (int ml=0; ml<2; ++ml){
        const int c0 = (w*2+ml)*16 + h4*4;
        const float4 gm = *(const float4*)(cn_gamma + c0);
        const float4 b2 = *(const float4*)(pw2_b + c0);
        #pragma unroll
        for (int nt=0; nt<4; ++nt){
            const int row = nt*16 + mcol;
            const int ad = row*512 + ((2*c0) ^ ((row&7)<<4));
            const float f0 = gm.x*(acc2[ml][nt].x + b2.x);
            const float f1 = gm.y*(acc2[ml][nt].y + b2.y);
            const float f2 = gm.z*(acc2[ml][nt].z + b2.z);
            const float f3 = gm.w*(acc2[ml][nt].w + b2.w);
            *(uint2*)(Xb + ad) = make_uint2(pack2(f0,f1), pack2(f2,f3));
        }
    }
    __syncthreads();
    #pragma unroll
    for (int p=0;p<25;p++){
        const int row = sP*32 + p;
        unsigned short* ptr = (unsigned short*)(Xb + row*512 + ((2*cP) ^ ((row&7)<<4)));
        const float r = (p&1) ? bf_hi(wvp[p>>1]) : bf_lo(wvp[p>>1]);
        *ptr = f2bf(bfu(*ptr) + r);
    }
    __syncthreads();

    {
        f32x4 a3[4];
        #pragma unroll
        for (int nt=0;nt<4;nt++) a3[nt]=0.f;
        #pragma unroll
        for (int kk=0; kk<8; ++kk){
            const short8 av = Pbv[((w<<3)+kk)*64 + lane];
            #pragma unroll
            for (int nt=0; nt<4; ++nt){
                const int row = nt*16 + mcol;
                const int ad = row*512 + ((kk*64 + h4*16) ^ ((row&7)<<4));
                const short8 bv = *(const short8*)(Xb + ad);
                a3[nt] = __builtin_amdgcn_mfma_f32_16x16x32_bf16(av, bv, a3[nt], 0,0,0);
            }
        }
        const float4 bb = *(const float4*)(bn1x1_b + w*16 + h4*4);
        float e5[5];
        #pragma unroll
        for (int a=0;a<5;a++){
            const float ta = -1.f + 0.5f*a;
            e5[a] = expf(-3.125f*ta*ta);
        }
        const float Sv = e5[0]+e5[1]+e5[2]+e5[3]+e5[4];
        const float invS = 1.0f/(Sv*Sv);
        float sA[2][4];
        #pragma unroll
        for (int s=0;s<2;s++)
            #pragma unroll
            for (int j=0;j<4;j++) sA[s][j]=0.f;
        #pragma unroll
        for (int nt=0; nt<4; ++nt){
            const int row = nt*16 + mcol;
            const int s = row>>5, p = row&31;
            if (p < 25){
                const int pa = p/5, pb = p - pa*5;
                const float g = e5[pa]*e5[pb];
                sA[s][0] += g*gelu_q(a3[nt].x + bb.x);
                sA[s][1] += g*gelu_q(a3[nt].y + bb.y);
                sA[s][2] += g*gelu_q(a3[nt].z + bb.z);
                sA[s][3] += g*gelu_q(a3[nt].w + bb.w);
            }
        }
        #pragma unroll
        for (int off=1; off<16; off<<=1){
            #pragma unroll
            for (int s=0;s<2;s++)
                #pragma unroll
                for (int j=0;j<4;j++) sA[s][j] += __shfl_xor(sA[s][j], off);
        }
        if (mcol == 0){
            const int o = w*16 + h4*4;
            #pragma unroll
            for (int s=0;s<2;s++){
                float* vo = vec_out + (n0+s)*192 + o;
                vo[0]=sA[s][0]*invS; vo[1]=sA[s][1]*invS;
                vo[2]=sA[s][2]*invS; vo[3]=sA[s][3]*invS;
            }
        }
    }
}

__global__ __launch_bounds__(512,4) void bn_branch_mfma(
    const float* __restrict__ bottleneck, const float* __restrict__ pos,
    const float* __restrict__ dw_w, const float* __restrict__ dw_b,
    const float* __restrict__ ln_g, const float* __restrict__ ln_b,
    const float* __restrict__ pw1_b, const float* __restrict__ pw2_b,
    const float* __restrict__ cn_gamma, const float* __restrict__ bn1x1_b,
    const short8* __restrict__ P1v, const short8* __restrict__ P2v,
    const short8* __restrict__ Pbv,
    float* __restrict__ vec_out)
{
    __shared__ __align__(16) unsigned char U[69184];
    bn_body<false>(U, blockIdx.x*2, threadIdx.x, bottleneck, nullptr, pos, dw_w, dw_b, ln_g, ln_b,
                   pw1_b, pw2_b, cn_gamma, bn1x1_b, P1v, P2v, Pbv, vec_out);
}

__global__ __launch_bounds__(512,4) void bn_branch_mfma_tr(
    const unsigned short* __restrict__ bnT, const float* __restrict__ pos,
    const float* __restrict__ dw_w, const float* __restrict__ dw_b,
    const float* __restrict__ ln_g, const float* __restrict__ ln_b,
    const float* __restrict__ pw1_b, const float* __restrict__ pw2_b,
    const float* __restrict__ cn_gamma, const float* __restrict__ bn1x1_b,
    const short8* __restrict__ P1v, const short8* __restrict__ P2v,
    const short8* __restrict__ Pbv,
    float* __restrict__ vec_out)
{
    __shared__ __align__(16) unsigned char U[69184];
    bn_body<true>(U, blockIdx.x*2, threadIdx.x, nullptr, bnT, pos, dw_w, dw_b, ln_g, ln_b,
                  pw1_b, pw2_b, cn_gamma, bn1x1_b, P1v, P2v, Pbv, vec_out);
}

// ---- bottleneck transpose: [256][128][128] f32 -> [128][128][256] bf16 (proven r14) ----
__global__ __launch_bounds__(256) void transpose_bn_kernel(
    const float* __restrict__ bn, unsigned short* __restrict__ bnT)
{
    __shared__ unsigned short T[256*66];
    const int b = blockIdx.x;
    const int y = b >> 1, x0 = (b & 1) << 6;
    const int t = threadIdx.x, lane = t & 63, w = t >> 6;
    for (int i = 0; i < 64; ++i){
        const int c = w*64 + i;
        T[c*66 + lane] = f2bf(bn[c*16384 + y*128 + x0 + lane]);
    }
    __syncthreads();
    const int x = t >> 2, q = (t & 3) * 64;
    #pragma unroll
    for (int h = 0; h < 8; ++h){
        const int cg = q + h*8;
        unsigned int v[4];
        #pragma unroll
        for (int j = 0; j < 4; ++j){
            const unsigned int a = T[(cg + 2*j    )*66 + x];
            const unsigned int bs = T[(cg + 2*j + 1)*66 + x];
            v[j] = a | (bs << 16);
        }
        *(uint4*)(bnT + ((size_t)(y*128) + x0 + x)*256 + cg) = make_uint4(v[0],v[1],v[2],v[3]);
    }
}

// ---- bn weight prepack (proven) ----
__global__ __launch_bounds__(256) void prepack_bn_kernel(
    const float* __restrict__ W1, const float* __restrict__ W2, const float* __restrict__ Wb,
    unsigned short* __restrict__ P1, unsigned short* __restrict__ P2, unsigned short* __restrict__ Pb)
{
    const int tid = blockIdx.x*256 + threadIdx.x;
    const float* src; unsigned short* dst; int row, col, stride, idx;
    if (tid < 32768){
        idx = tid;
        const int frag = idx>>6, l = idx&63;
        row = (frag>>3)*16 + (l&15); col = (frag&7)*32 + (l>>4)*8; stride = 256;
        src = W1; dst = P1;
    } else if (tid < 65536){
        idx = tid - 32768;
        const int frag = idx>>6, l = idx&63;
        row = (frag>>5)*16 + (l&15); col = (frag&31)*32 + (l>>4)*8; stride = 1024;
        src = W2; dst = P2;
    } else if (tid < 69632){
        idx = tid - 65536;
        const int frag = idx>>6, l = idx&63;
        row = (frag>>3)*16 + (l&15); col = (frag&7)*32 + (l>>4)*8; stride = 256;
        src = Wb; dst = Pb;
    } else return;
    const float* s = src + row*stride + col;
    unsigned int v[4];
    #pragma unroll
    for (int j=0;j<4;j++) v[j] = pack2(s[2*j], s[2*j+1]);
    *(uint4*)(dst + (size_t)idx*8) = make_uint4(v[0],v[1],v[2],v[3]);
}

// ---------------- Stem weight prepack (proven r9) ----------------
__global__ __launch_bounds__(256) void prepack_kernel(
    const float* __restrict__ W1, const float* __restrict__ W2,
    unsigned short* __restrict__ Ap)
{
    const int tid = blockIdx.x*256 + threadIdx.x;
    if (tid >= 9216) return;
    const int conv = tid / 4608;
    const int r = tid - conv*4608;
    const int frag = r >> 6, l = r & 63;
    const int k  = frag >> 3;
    const int kt = (frag >> 1) & 3;
    const int wo = frag & 1;
    const float* W = conv ? W2 : W1;
    const int o  = wo*32 + (l & 31);
    const int c0 = kt*16 + (l >> 5)*8;
    unsigned int v[4];
    #pragma unroll
    for (int jj=0; jj<4; jj++){
        const float f0 = W[o*576 + (c0+2*jj  )*9 + k];
        const float f1 = W[o*576 + (c0+2*jj+1)*9 + k];
        v[jj] = pack2(f0, f1);
    }
    *(uint4*)(Ap + (size_t)tid*8) = make_uint4(v[0], v[1], v[2], v[3]);
}

// ---------------- vis transpose (proven r13) ----------------
__global__ __launch_bounds__(256) void transpose_vis_kernel(
    const float* __restrict__ vis, unsigned short* __restrict__ visT)
{
    __shared__ unsigned short T[64*66];
    const int b = blockIdx.x;
    const int y = b >> 4, x0 = (b & 15) << 6;
    const int t = threadIdx.x, lane = t & 63, w = t >> 6;
    #pragma unroll
    for (int i = 0; i < 16; ++i){
        const int c = w*16 + i;
        T[c*66 + lane] = f2bf(vis[c*1048576 + y*1024 + x0 + lane]);
    }
    __syncthreads();
    const int x = t >> 2, cg0 = (t & 3) * 16;
    #pragma unroll
    for (int h = 0; h < 2; ++h){
        const int cg = cg0 + h*8;
        unsigned int v[4];
        #pragma unroll
        for (int j = 0; j < 4; ++j){
            const unsigned int a = T[(cg + 2*j    )*66 + x];
            const unsigned int bsh = T[(cg + 2*j + 1)*66 + x];
            v[j] = a | (bsh << 16);
        }
        *(uint4*)(visT + ((size_t)(y*1024) + x0 + x)*64 + cg) = make_uint4(v[0],v[1],v[2],v[3]);
    }
}

// ================= Stem body (proven r9-r14) =================
#define STEM_CONV32(SRC, AP)                                                        \
    _Pragma("unroll")                                                               \
    for (int k=0;k<9;k++){                                                          \
        int tj[3];                                                                  \
        _Pragma("unroll")                                                           \
        for (int j=0;j<3;j++)                                                       \
            tj[j] = (int)sTab[m*90 + (j<cnt ? st+j : st)*9 + k];                    \
        _Pragma("unroll")                                                           \
        for (int kt=0;kt<4;kt++){                                                   \
            const short8 av = (AP)[(k*8 + kt*2 + wo)*64 + lane];                    \
            const int cb = kt*32 + hi16;                                            \
            _Pragma("unroll")                                                       \
            for (int j=0;j<3;j++){                                                  \
                if (j < cnt){                                                       \
                    const short8 bv = *(const short8*)((SRC) + (tj[j] ^ cb));       \
                    acc[j] = __builtin_amdgcn_mfma_f32_32x32x16_bf16(av, bv, acc[j], 0,0,0); \
                }                                                                   \
            }                                                                       \
        }                                                                           \
    }

template<bool TR>
__device__ __forceinline__ void stem_body(
    unsigned char* __restrict__ U, int n, int t,
    const float* __restrict__ vis, const unsigned short* __restrict__ visT,
    const float* __restrict__ pos,
    const short8* __restrict__ Ap1,
    const float* __restrict__ st1_b, const float* __restrict__ st2_b,
    float* __restrict__ vec_out)
{
    unsigned char* sXt = U;
    unsigned short* sTab = (unsigned short*)(U + 37120);
    float (*redS)[4] = (float(*)[4])(U + 42880);

    const int lane = t & 63;
    const int m = lane & 31;
    const int hi = lane >> 5;
    const int hi16 = hi*16;
    const int w = t >> 6;
    const int wo = w & 1;
    const int nh = w >> 1;
    const int st  = nh*3 - (nh==3 ? 1 : 0);
    const int cnt = (nh < 2) ? 3 : 2;

    const float fpx0 = pos[2*n], fpy0 = pos[2*n+1];
    const float fpx = floorf(fpx0), fpy = floorf(fpy0);
    const int ix0 = (int)fpx - 8, iy0 = (int)fpy - 8;
    const float fx = fpx0-fpx, fy = fpy0-fpy;
    const float w00=(1.f-fy)*(1.f-fx), w01=(1.f-fy)*fx, w10=fy*(1.f-fx), w11=fy*fx;

    if (t < 32) *(unsigned int*)(sXt + 289*128 + t*4) = 0u;

    for (int idx = t; idx < 32*90; idx += 512){
        const int mm = idx/90, rem = idx - mm*90;
        const int nt = rem/9, k = rem - nt*9;
        const int p = nt*32 + mm;
        int pp = 289;
        if (p < 289){
            const int py = (p*241)>>12, px = p - py*17;
            const int y = py + k/3 - 1, x = px + (k - (k/3)*3) - 1;
            if (((unsigned)y < 17u) && ((unsigned)x < 17u)) pp = y*17 + x;
        }
        sTab[idx] = (unsigned short)(pp*128 + ((pp&7)<<4));
    }

    if (TR){
        for (int idx = t; idx < 289*8; idx += 512){
            const int p = idx >> 3, cg = (idx & 7) * 8;
            const int py = (p*241)>>12, px = p - py*17;
            const unsigned short* q = visT + (size_t)((iy0+py)*1024 + (ix0+px))*64 + cg;
            const uint4 q00 = *(const uint4*)(q);
            const uint4 q01 = *(const uint4*)(q + 64);
            const uint4 q10 = *(const uint4*)(q + 65536);
            const uint4 q11 = *(const uint4*)(q + 65536 + 64);
            unsigned int o[4];
            #pragma unroll
            for (int j=0;j<4;j++){
                const unsigned int u00=((const unsigned int*)&q00)[j];
                const unsigned int u01=((const unsigned int*)&q01)[j];
                const unsigned int u10=((const unsigned int*)&q10)[j];
                const unsigned int u11=((const unsigned int*)&q11)[j];
                const float lo = bf_lo(u00)*w00 + bf_lo(u01)*w01 + bf_lo(u10)*w10 + bf_lo(u11)*w11;
                const float hv = bf_hi(u00)*w00 + bf_hi(u01)*w01 + bf_hi(u10)*w10 + bf_hi(u11)*w11;
                o[j] = pack2(lo, hv);
            }
            *(uint4*)(sXt + p*128 + ((2*cg) ^ ((p&7)<<4))) = make_uint4(o[0],o[1],o[2],o[3]);
        }
    } else {
        for (int task = t; task < 64*17; task += 512){
            const int c  = task & 63;
            const int py = task >> 6;
            const float* r0 = vis + c*1048576 + (iy0+py)*1024 + ix0;
            float a[18], b[18];
            #pragma unroll
            for (int kk=0; kk<18; kk++){ a[kk]=r0[kk]; b[kk]=r0[1024+kk]; }
            #pragma unroll
            for (int px=0; px<17; px++){
                const float v = w00*a[px] + w01*a[px+1] + w10*b[px] + w11*b[px+1];
                const int p = py*17 + px;
                *(unsigned short*)(sXt + p*128 + ((2*c) ^ ((p&7)<<4))) = f2bf(v);
            }
        }
    }
    __syncthreads();

    f32x16 acc[3];
    #pragma unroll
    for (int j=0;j<3;j++) acc[j] = 0.f;
    STEM_CONV32(sXt, Ap1)

    uint2 pk[3][4];
    {
        float4 b4[4];
        #pragma unroll
        for (int rg=0;rg<4;rg++) b4[rg] = *(const float4*)(st1_b + wo*32 + 8*rg + 4*hi);
        #pragma unroll
        for (int j=0;j<3;j++){
            if (j < cnt){
                #pragma unroll
                for (int rg=0;rg<4;rg++){
                    const float v0 = gelu_q(acc[j][4*rg+0] + b4[rg].x);
                    const float v1 = gelu_q(acc[j][4*rg+1] + b4[rg].y);
                    const float v2 = gelu_q(acc[j][4*rg+2] + b4[rg].z);
                    const float v3 = gelu_q(acc[j][4*rg+3] + b4[rg].w);
                    pk[j][rg] = make_uint2(pack2(v0,v1), pack2(v2,v3));
                }
            }
        }
    }
    __syncthreads();

    #pragma unroll
    for (int j=0;j<3;j++){
        if (j < cnt){
            const int p = (st+j)*32 + m;
            if (p < 289){
                const int swz = (p&7)<<4;
                #pragma unroll
                for (int rg=0;rg<4;rg++){
                    const int ch0 = wo*32 + 8*rg + 4*hi;
                    *(uint2*)(sXt + p*128 + ((2*ch0) ^ swz)) = pk[j][rg];
                }
            }
        }
    }
    __syncthreads();

    const short8* Ap2 = Ap1 + 4608;
    #pragma unroll
    for (int j=0;j<3;j++) acc[j] = 0.f;
    STEM_CONV32(sXt, Ap2)

    {
        float4 b4[4];
        #pragma unroll
        for (int rg=0;rg<4;rg++) b4[rg] = *(const float4*)(st2_b + wo*32 + 8*rg + 4*hi);
        float s[16];
        #pragma unroll
        for (int r=0;r<16;r++) s[r]=0.f;
        #pragma unroll
        for (int j=0;j<3;j++){
            if (j < cnt){
                const int p = (st+j)*32 + m;
                if (p < 289){
                    const int py = (p*241)>>12;
                    const int px = p - py*17;
                    const float ty = -1.f + 0.125f*py;
                    const float tx = -1.f + 0.125f*px;
                    const float g = expf(-3.125f*(ty*ty + tx*tx));
                    #pragma unroll
                    for (int rg=0;rg<4;rg++){
                        s[4*rg+0] += g*gelu_q(acc[j][4*rg+0] + b4[rg].x);
                        s[4*rg+1] += g*gelu_q(acc[j][4*rg+1] + b4[rg].y);
                        s[4*rg+2] += g*gelu_q(acc[j][4*rg+2] + b4[rg].z);
                        s[4*rg+3] += g*gelu_q(acc[j][4*rg+3] + b4[rg].w);
                    }
                }
            }
        }
        #pragma unroll
        for (int off=1; off<32; off<<=1){
            #pragma unroll
            for (int r=0;r<16;r++) s[r] += __shfl_xor(s[r], off);
        }
        if (m == 0){
            #pragma unroll
            for (int rg=0;rg<4;rg++)
                #pragma unroll
                for (int e=0;e<4;e++)
                    redS[wo*32 + 8*rg + 4*hi + e][nh] = s[4*rg+e];
        }
    }
    __syncthreads();
    if (t < 64){
        float Sv = 0.f;
        #pragma unroll
        for (int j=0;j<17;j++){
            const float tj = -1.f + 0.125f*j;
            Sv += expf(-3.125f*tj*tj);
        }
        vec_out[n*192+128+t] = (redS[t][0] + redS[t][1] + redS[t][2] + redS[t][3]) / (Sv*Sv);
    }
}

__global__ __launch_bounds__(512,4) void stem_kernel_tr(
    const unsigned short* __restrict__ visT, const float* __restrict__ pos,
    const short8* __restrict__ Ap1,
    const float* __restrict__ st1_b, const float* __restrict__ st2_b,
    float* __restrict__ vec_out)
{
    __shared__ __align__(16) unsigned char U[43904];
    stem_body<true>(U, blockIdx.x, threadIdx.x, nullptr, visT, pos, Ap1, st1_b, st2_b, vec_out);
}

__global__ __launch_bounds__(512,4) void stem_branch_kernel(
    const float* __restrict__ vis, const float* __restrict__ pos,
    const short8* __restrict__ Ap1,
    const float* __restrict__ st1_b, const float* __restrict__ st2_b,
    float* __restrict__ vec_out)
{
    __shared__ __align__(16) unsigned char U[43904];
    stem_body<false>(U, blockIdx.x, threadIdx.x, vis, nullptr, pos, Ap1, st1_b, st2_b, vec_out);
}

// ---------------- Head: 16 samples/block (proven) ----------------
__global__ __launch_bounds__(128) void head16_kernel(
    const float* __restrict__ vec, const float* __restrict__ p2s,
    const float* __restrict__ h1_w, const float* __restrict__ h1_b,
    const float* __restrict__ h2_w, const float* __restrict__ h2_b,
    const float* __restrict__ h3_w, const float* __restrict__ h3_b,
    float* __restrict__ out, int N)
{
    __shared__ float v[16][192];
    __shared__ float x1s[16][132];
    __shared__ float x2s[16][132];
    __shared__ float o3s[16][4];
    const int n0 = blockIdx.x*16, t = threadIdx.x;

    for (int idx=t; idx<16*192; idx+=128){
        const int s = idx/192, k = idx - s*192;
        v[s][k] = vec[n0*192 + idx];
    }
    __syncthreads();
    {
        const int o = t;
        float acc[16];
        const float b = h1_b[o];
        #pragma unroll
        for (int s=0;s<16;s++) acc[s]=b;
        const float4* wr = (const float4*)(h1_w + o*192);
        for (int k4=0;k4<48;k4++){
            const float4 wv4 = wr[k4];
            #pragma unroll
            for (int s=0;s<16;s++){
                const float4 vv = *(const float4*)&v[s][k4*4];
                acc[s] += wv4.x*vv.x + wv4.y*vv.y + wv4.z*vv.z + wv4.w*vv.w;
            }
        }
        #pragma unroll
        for (int s=0;s<16;s++) x1s[s][o] = gelu_f(acc[s]);
    }
    __syncthreads();
    {
        const int o = t;
        float acc[16];
        const float b = h2_b[o];
        #pragma unroll
        for (int s=0;s<16;s++) acc[s]=b;
        const float4* wr = (const float4*)(h2_w + o*128);
        for (int k4=0;k4<32;k4++){
            const float4 wv4 = wr[k4];
            #pragma unroll
            for (int s=0;s<16;s++){
                const float4 vv = *(const float4*)&x1s[s][k4*4];
                acc[s] += wv4.x*vv.x + wv4.y*vv.y + wv4.z*vv.z + wv4.w*vv.w;
            }
        }
        #pragma unroll
        for (int s=0;s<16;s++) x2s[s][o] = gelu_f(acc[s]);
    }
    __syncthreads();
    if (t < 48){
        const int j = t>>4, s = t&15;
        float a = h3_b[j];
        const float* wr = h3_w + j*128;
        for (int k=0;k<128;k++) a += x2s[s][k]*wr[k];
        o3s[s][j] = a;
    }
    __syncthreads();
    if (t < 16){
        const int s = t, n = n0 + s;
        const float dx = o3s[s][0], dy = o3s[s][1];
        float ls = o3s[s][2];
        ls = ls < -6.f ? -6.f : (ls > 3.f ? 3.f : ls);
        const float s0 = p2s[n*4+0]*dx + p2s[n*4+1]*dy;
        const float s1 = p2s[n*4+2]*dx + p2s[n*4+3]*dy;
        const float conf = 1.0f/fmaxf(expf(ls), 1e-4f);
        out[2*n]   = s0;
        out[2*n+1] = s1;
        out[2*N+n] = dx;
        out[3*N+n] = dy;
        out[4*N+n] = ls;
        out[5*N+n] = conf;
    }
}

extern "C" void kernel_launch(void* const* d_in, const int* in_sizes, int n_in,
                              void* d_out, int out_size, void* d_ws, size_t ws_size,
                              hipStream_t stream)
{
    (void)n_in; (void)out_size;
    const float* bottleneck = (const float*)d_in[0];
    const float* vis        = (const float*)d_in[1];
    const float* pos        = (const float*)d_in[2];
    const float* p2s        = (const float*)d_in[3];
    const float* dw_w  = (const float*)d_in[8];
    const float* dw_b  = (const float*)d_in[9];
    const float* ln_g  = (const float*)d_in[10];
    const float* ln_b  = (const float*)d_in[11];
    const float* pw1_w = (const float*)d_in[12];
    const float* pw1_b = (const float*)d_in[13];
    const float* pw2_w = (const float*)d_in[14];
    const float* pw2_b = (const float*)d_in[15];
    const float* gam   = (const float*)d_in[16];
    const float* b1w   = (const float*)d_in[17];
    const float* b1b   = (const float*)d_in[18];
    const float* s1w   = (const float*)d_in[19];
    const float* s1b   = (const float*)d_in[20];
    const float* s2w   = (const float*)d_in[21];
    const float* s2b   = (const float*)d_in[22];
    const float* h1w   = (const float*)d_in[23];
    const float* h1b   = (const float*)d_in[24];
    const float* h2w   = (const float*)d_in[25];
    const float* h2b   = (const float*)d_in[26];
    const float* h3w   = (const float*)d_in[27];
    const float* h3b   = (const float*)d_in[28];

    const int N = in_sizes[2]/2;            // 4096
    char* ws = (char*)d_ws;
    float* vec = (float*)ws;                                  // 3,145,728
    unsigned short* Apack = (unsigned short*)(ws + 3145728);  //   147,456
    unsigned short* P1    = (unsigned short*)(ws + 3293184);  //   524,288
    unsigned short* P2    = (unsigned short*)(ws + 3817472);  //   524,288
    unsigned short* Pb    = (unsigned short*)(ws + 4341760);  //    65,536
    unsigned short* visT  = (unsigned short*)(ws + 4407296);  // 134,217,728
    unsigned short* bnT   = (unsigned short*)(ws + 4407296 + 134217728ull); // 8,388,608
    const size_t need_mfma = 4407296u;
    const size_t need_tr   = 4407296u + 134217728ull;
    const size_t need_full = need_tr + 8388608ull;
    const size_t vec_bytes = (size_t)N*192*sizeof(float);

    hipMemsetAsync(d_ws, 0, vec_bytes, stream);
    prepack_kernel<<<36, 256, 0, stream>>>(s1w, s2w, Apack);

    if (ws_size >= need_full){
        prepack_bn_kernel<<<272, 256, 0, stream>>>(pw1_w, pw2_w, b1w, P1, P2, Pb);
        transpose_bn_kernel<<<256, 256, 0, stream>>>(bottleneck, bnT);
        transpose_vis_kernel<<<16384, 256, 0, stream>>>(vis, visT);
        stem_kernel_tr<<<N, 512, 0, stream>>>(visT, pos, (const short8*)Apack, s1b, s2b, vec);
        bn_branch_mfma_tr<<<N/2, 512, 0, stream>>>(bnT, pos, dw_w, dw_b, ln_g, ln_b,
                                                   pw1_b, pw2_b, gam, b1b,
                                                   (const short8*)P1, (const short8*)P2, (const short8*)Pb,
                                                   vec);
    } else if (ws_size >= need_tr){
        prepack_bn_kernel<<<272, 256, 0, stream>>>(pw1_w, pw2_w, b1w, P1, P2, Pb);
        transpose_vis_kernel<<<16384, 256, 0, stream>>>(vis, visT);
        stem_kernel_tr<<<N, 512, 0, stream>>>(visT, pos, (const short8*)Apack, s1b, s2b, vec);
        bn_branch_mfma<<<N/2, 512, 0, stream>>>(bottleneck, pos, dw_w, dw_b, ln_g, ln_b,
                                                pw1_b, pw2_b, gam, b1b,
                                                (const short8*)P1, (const short8*)P2, (const short8*)Pb,
                                                vec);
    } else {
        prepack_bn_kernel<<<272, 256, 0, stream>>>(pw1_w, pw2_w, b1w, P1, P2, Pb);
        bn_branch_mfma<<<N/2, 512, 0, stream>>>(bottleneck, pos, dw_w, dw_b, ln_g, ln_b,
                                                pw1_b, pw2_b, gam, b1b,
                                                (const short8*)P1, (const short8*)P2, (const short8*)Pb,
                                                vec);
        stem_branch_kernel<<<N, 512, 0, stream>>>(vis, pos, (const short8*)Apack, s1b, s2b, vec);
    }
    head16_kernel<<<N/16, 128, 0, stream>>>(vec, p2s, h1w, h1b, h2w, h2b, h3w, h3b,
                                            (float*)d_out, N);
}